// Round 1
// baseline (2836.312 us; speedup 1.0000x reference)
//
#include <hip/hip_runtime.h>
#include <math.h>

#define NN 50000      // nodes
#define NE 800000     // edges (without self loops)
#define EP 850000     // edges + self loops
#define EDF 16        // edge feature dim
#define C1 128        // heads*hid layer1
#define HID 32
#define OUTF 64
#define NG 64
#define SLOPE 0.2f

static inline int cdiv(long a, long b){ return (int)((a + b - 1) / b); }

__device__ __forceinline__ unsigned f2ord(float f){
  unsigned u = __float_as_uint(f);
  return (u & 0x80000000u) ? ~u : (u | 0x80000000u);
}
__device__ __forceinline__ float ord2f(unsigned u){
  unsigned v = (u & 0x80000000u) ? (u & 0x7FFFFFFFu) : ~u;
  return __uint_as_float(v);
}
__device__ __forceinline__ float lrelu(float x){ return x >= 0.f ? x : SLOPE * x; }

// ---- mean of edge_attr over rows (partial sums via atomics) ----
__global__ void k_mean_ea(const float* __restrict__ ea, float* __restrict__ sumEA){
  int c = threadIdx.x & 15;
  int r0 = threadIdx.x >> 4;   // 0..15
  float acc = 0.f;
  for (long r = (long)blockIdx.x * 16 + r0; r < NE; r += (long)gridDim.x * 16)
    acc += ea[r * EDF + c];
  __shared__ float s[256];
  s[threadIdx.x] = acc;
  __syncthreads();
  for (int stride = 128; stride >= 16; stride >>= 1){
    if (threadIdx.x < stride) s[threadIdx.x] += s[threadIdx.x + stride];
    __syncthreads();
  }
  if (threadIdx.x < 16) atomicAdd(&sumEA[c], s[threadIdx.x]);
}

// ---- tiny prep: meanEA, M1[4][16], M2[16], self-loop a_edge constants ----
__global__ void k_prep(const float* __restrict__ sumEA,
                       const float* __restrict__ We1, const float* __restrict__ att_e1,
                       const float* __restrict__ We2, const float* __restrict__ att_e2,
                       float* __restrict__ meanEA, float* __restrict__ M1,
                       float* __restrict__ M2, float* __restrict__ aeSL1,
                       float* __restrict__ aeSL2){
  int t = threadIdx.x; // 128 threads
  if (t < 16) meanEA[t] = sumEA[t] * (1.0f / NE);
  if (t < 64){
    int h = t >> 4, d = t & 15;
    float s = 0.f;
    for (int c = 0; c < HID; c++) s += We1[d * C1 + h * HID + c] * att_e1[h * HID + c];
    M1[h * 16 + d] = s;
  }
  if (t >= 64 && t < 80){
    int d = t - 64;
    float s = 0.f;
    for (int c = 0; c < OUTF; c++) s += We2[d * OUTF + c] * att_e2[c];
    M2[d] = s;
  }
  __syncthreads();
  if (t < 4){
    float s = 0.f;
    for (int d = 0; d < 16; d++) s += meanEA[d] * M1[t * 16 + d];
    aeSL1[t] = s;
  }
  if (t == 4){
    float s = 0.f;
    for (int d = 0; d < 16; d++) s += meanEA[d] * M2[d];
    *aeSL2 = s;
  }
}

// ---- f32 GEMM: C[M,Ncols] = A[M,K] @ B[K,Ncols]; BM=BN=64, BK=16, 256 thr ----
__global__ __launch_bounds__(256) void k_gemm(const float* __restrict__ A,
                                              const float* __restrict__ B,
                                              float* __restrict__ C,
                                              int M, int Ncols, int K){
  __shared__ float As[16][64];
  __shared__ float Bs[16][64];
  int tid = threadIdx.x;
  int row0 = blockIdx.x * 64, col0 = blockIdx.y * 64;
  int tx = tid & 15, ty = tid >> 4;       // 16x16 threads, 4x4 each
  int lrow = tid >> 2, lkq = tid & 3;     // A-tile load mapping
  int bk = tid >> 4, bc = tid & 15;       // B-tile load mapping
  float acc[4][4] = {};
  for (int k0 = 0; k0 < K; k0 += 16){
    float4 a4 = make_float4(0.f, 0.f, 0.f, 0.f);
    int gr = row0 + lrow;
    if (gr < M) a4 = *(const float4*)&A[(long)gr * K + k0 + lkq * 4];
    As[lkq * 4 + 0][lrow] = a4.x; As[lkq * 4 + 1][lrow] = a4.y;
    As[lkq * 4 + 2][lrow] = a4.z; As[lkq * 4 + 3][lrow] = a4.w;
    *(float4*)&Bs[bk][bc * 4] = *(const float4*)&B[(long)(k0 + bk) * Ncols + col0 + bc * 4];
    __syncthreads();
#pragma unroll
    for (int k = 0; k < 16; k++){
      float4 a = *(float4*)&As[k][ty * 4];
      float4 b = *(float4*)&Bs[k][tx * 4];
      acc[0][0] += a.x*b.x; acc[0][1] += a.x*b.y; acc[0][2] += a.x*b.z; acc[0][3] += a.x*b.w;
      acc[1][0] += a.y*b.x; acc[1][1] += a.y*b.y; acc[1][2] += a.y*b.z; acc[1][3] += a.y*b.w;
      acc[2][0] += a.z*b.x; acc[2][1] += a.z*b.y; acc[2][2] += a.z*b.z; acc[2][3] += a.z*b.w;
      acc[3][0] += a.w*b.x; acc[3][1] += a.w*b.y; acc[3][2] += a.w*b.z; acc[3][3] += a.w*b.w;
    }
    __syncthreads();
  }
#pragma unroll
  for (int i = 0; i < 4; i++){
    int r = row0 + ty * 4 + i;
    if (r < M){
      float4 v = make_float4(acc[i][0], acc[i][1], acc[i][2], acc[i][3]);
      *(float4*)&C[(long)r * Ncols + col0 + tx * 4] = v;
    }
  }
}

// ---- layer1 attention dots: a_src/a_dst per (node, head) ----
__global__ void k_attdot1(const float* __restrict__ h1, const float* __restrict__ att_src,
                          const float* __restrict__ att_dst,
                          float* __restrict__ a_src, float* __restrict__ a_dst){
  long idx = (long)blockIdx.x * blockDim.x + threadIdx.x;
  if (idx >= (long)NN * 4) return;
  int h = (int)(idx & 3); long n = idx >> 2;
  const float* hp = h1 + n * C1 + h * HID;
  float ss = 0.f, sd = 0.f;
#pragma unroll
  for (int i = 0; i < HID; i += 4){
    float4 v = *(const float4*)&hp[i];
    float4 as = *(const float4*)&att_src[h * HID + i];
    float4 ad = *(const float4*)&att_dst[h * HID + i];
    ss += v.x*as.x + v.y*as.y + v.z*as.z + v.w*as.w;
    sd += v.x*ad.x + v.y*ad.y + v.z*ad.z + v.w*ad.w;
  }
  a_src[idx] = ss; a_dst[idx] = sd;
}

// ---- layer1 pass A: alpha + atomicMax m ----
__global__ void k_edgeA1(const int* __restrict__ src, const int* __restrict__ dst,
                         const float* __restrict__ ea, const float* __restrict__ M1,
                         const float* __restrict__ aeSL1,
                         const float* __restrict__ a_src, const float* __restrict__ a_dst,
                         float* __restrict__ alpha, unsigned* __restrict__ m1){
  long e = (long)blockIdx.x * blockDim.x + threadIdx.x;
  if (e >= EP) return;
  int s, d;
  float ae[4];
  if (e < NE){
    s = src[e]; d = dst[e];
    float eav[16];
    const float4* p = (const float4*)(ea + e * EDF);
    *(float4*)&eav[0]  = p[0]; *(float4*)&eav[4]  = p[1];
    *(float4*)&eav[8]  = p[2]; *(float4*)&eav[12] = p[3];
#pragma unroll
    for (int h = 0; h < 4; h++){
      const float* mr = M1 + h * 16;
      float sdot = 0.f;
#pragma unroll
      for (int dd = 0; dd < 16; dd++) sdot += eav[dd] * mr[dd];
      ae[h] = sdot;
    }
  } else {
    s = d = (int)(e - NE);
#pragma unroll
    for (int h = 0; h < 4; h++) ae[h] = aeSL1[h];
  }
  float4 asv = *(const float4*)&a_src[(long)s * 4];
  float4 adv = *(const float4*)&a_dst[(long)d * 4];
  float al0 = lrelu(asv.x + adv.x + ae[0]);
  float al1 = lrelu(asv.y + adv.y + ae[1]);
  float al2 = lrelu(asv.z + adv.z + ae[2]);
  float al3 = lrelu(asv.w + adv.w + ae[3]);
  *(float4*)&alpha[e * 4] = make_float4(al0, al1, al2, al3);
  atomicMax(&m1[(long)d * 4 + 0], f2ord(al0));
  atomicMax(&m1[(long)d * 4 + 1], f2ord(al1));
  atomicMax(&m1[(long)d * 4 + 2], f2ord(al2));
  atomicMax(&m1[(long)d * 4 + 3], f2ord(al3));
}

// ---- layer1 pass B: ex = exp(alpha - max), atomicAdd denom ----
__global__ void k_edgeB1(const int* __restrict__ dst, float* __restrict__ alpha,
                         const unsigned* __restrict__ m1, float* __restrict__ denom){
  long e = (long)blockIdx.x * blockDim.x + threadIdx.x;
  if (e >= EP) return;
  int d = (e < NE) ? dst[e] : (int)(e - NE);
  float4 al = *(const float4*)&alpha[e * 4];
  uint4 mu = *(const uint4*)&m1[(long)d * 4];
  float4 ex;
  ex.x = expf(al.x - ord2f(mu.x));
  ex.y = expf(al.y - ord2f(mu.y));
  ex.z = expf(al.z - ord2f(mu.z));
  ex.w = expf(al.w - ord2f(mu.w));
  *(float4*)&alpha[e * 4] = ex;   // reuse buffer for ex
  atomicAdd(&denom[(long)d * 4 + 0], ex.x);
  atomicAdd(&denom[(long)d * 4 + 1], ex.y);
  atomicAdd(&denom[(long)d * 4 + 2], ex.z);
  atomicAdd(&denom[(long)d * 4 + 3], ex.w);
}

// ---- layer1 pass C: out1[dst] += h1[src] * coef ; 32 threads per edge ----
__global__ void k_edgeC1(const int* __restrict__ src, const int* __restrict__ dst,
                         const float* __restrict__ h1, const float* __restrict__ ex,
                         const float* __restrict__ denom, float* __restrict__ out1){
  long t = (long)blockIdx.x * blockDim.x + threadIdx.x;
  long e = t >> 5; int j = (int)(t & 31);
  if (e >= EP) return;
  int s, d;
  if (e < NE){ s = src[e]; d = dst[e]; } else { s = d = (int)(e - NE); }
  int h = j >> 3;
  float coef = ex[e * 4 + h] / (denom[(long)d * 4 + h] + 1e-16f);
  float4 v = *(const float4*)&h1[(long)s * C1 + j * 4];
  float* o = &out1[(long)d * C1 + j * 4];
  atomicAdd(o + 0, v.x * coef);
  atomicAdd(o + 1, v.y * coef);
  atomicAdd(o + 2, v.z * coef);
  atomicAdd(o + 3, v.w * coef);
}

// ---- bias + ELU in place ----
__global__ void k_elu(float* __restrict__ x, const float* __restrict__ b){
  long idx = (long)blockIdx.x * blockDim.x + threadIdx.x;
  if (idx >= (long)NN * C1) return;
  float v = x[idx] + b[idx & 127];
  x[idx] = v > 0.f ? v : expf(v) - 1.f;
}

// ---- layer2 attention dots (1 head, 64 ch) ----
__global__ void k_attdot2(const float* __restrict__ h2, const float* __restrict__ att_src,
                          const float* __restrict__ att_dst,
                          float* __restrict__ a_src, float* __restrict__ a_dst){
  long n = (long)blockIdx.x * blockDim.x + threadIdx.x;
  if (n >= NN) return;
  const float* hp = h2 + n * OUTF;
  float ss = 0.f, sd = 0.f;
#pragma unroll
  for (int i = 0; i < OUTF; i += 4){
    float4 v = *(const float4*)&hp[i];
    float4 as = *(const float4*)&att_src[i];
    float4 ad = *(const float4*)&att_dst[i];
    ss += v.x*as.x + v.y*as.y + v.z*as.z + v.w*as.w;
    sd += v.x*ad.x + v.y*ad.y + v.z*ad.z + v.w*ad.w;
  }
  a_src[n] = ss; a_dst[n] = sd;
}

// ---- layer2 pass A ----
__global__ void k_edgeA2(const int* __restrict__ src, const int* __restrict__ dst,
                         const float* __restrict__ ea, const float* __restrict__ M2,
                         const float* __restrict__ aeSL2,
                         const float* __restrict__ a_src, const float* __restrict__ a_dst,
                         float* __restrict__ alpha, unsigned* __restrict__ m2){
  long e = (long)blockIdx.x * blockDim.x + threadIdx.x;
  if (e >= EP) return;
  int s, d;
  float ae;
  if (e < NE){
    s = src[e]; d = dst[e];
    float sdot = 0.f;
    const float4* p = (const float4*)(ea + e * EDF);
    float4 v0 = p[0], v1 = p[1], v2 = p[2], v3 = p[3];
    sdot += v0.x*M2[0] + v0.y*M2[1] + v0.z*M2[2] + v0.w*M2[3];
    sdot += v1.x*M2[4] + v1.y*M2[5] + v1.z*M2[6] + v1.w*M2[7];
    sdot += v2.x*M2[8] + v2.y*M2[9] + v2.z*M2[10] + v2.w*M2[11];
    sdot += v3.x*M2[12] + v3.y*M2[13] + v3.z*M2[14] + v3.w*M2[15];
    ae = sdot;
  } else { s = d = (int)(e - NE); ae = *aeSL2; }
  float al = lrelu(a_src[s] + a_dst[d] + ae);
  alpha[e] = al;
  atomicMax(&m2[d], f2ord(al));
}

// ---- layer2 pass B ----
__global__ void k_edgeB2(const int* __restrict__ dst, float* __restrict__ alpha,
                         const unsigned* __restrict__ m2, float* __restrict__ denom){
  long e = (long)blockIdx.x * blockDim.x + threadIdx.x;
  if (e >= EP) return;
  int d = (e < NE) ? dst[e] : (int)(e - NE);
  float ex = expf(alpha[e] - ord2f(m2[d]));
  alpha[e] = ex;
  atomicAdd(&denom[d], ex);
}

// ---- layer2 pass C: out2[dst] += h2[src]*coef ; 16 threads/edge ----
__global__ void k_edgeC2(const int* __restrict__ src, const int* __restrict__ dst,
                         const float* __restrict__ h2, const float* __restrict__ ex,
                         const float* __restrict__ denom, float* __restrict__ out2){
  long t = (long)blockIdx.x * blockDim.x + threadIdx.x;
  long e = t >> 4; int j = (int)(t & 15);
  if (e >= EP) return;
  int s, d;
  if (e < NE){ s = src[e]; d = dst[e]; } else { s = d = (int)(e - NE); }
  float coef = ex[e] / (denom[d] + 1e-16f);
  float4 v = *(const float4*)&h2[(long)s * OUTF + j * 4];
  float* o = &out2[(long)d * OUTF + j * 4];
  atomicAdd(o + 0, v.x * coef);
  atomicAdd(o + 1, v.y * coef);
  atomicAdd(o + 2, v.z * coef);
  atomicAdd(o + 3, v.w * coef);
}

// ---- pool: batch sorted -> one block per graph, binary-search bounds ----
__global__ void k_pool(const float* __restrict__ out2, const int* __restrict__ batch,
                       const float* __restrict__ b2, float* __restrict__ out){
  int g = blockIdx.x;
  int lo = 0, hi = NN;
  while (lo < hi){ int mid = (lo + hi) >> 1; if (batch[mid] < g) lo = mid + 1; else hi = mid; }
  int lo2 = lo, hi2 = NN;
  { int a = lo, b = NN; while (a < b){ int mid = (a + b) >> 1; if (batch[mid] < g + 1) a = mid + 1; else b = mid; } hi2 = a; }
  int c = threadIdx.x & 63, r = threadIdx.x >> 6;
  float acc = 0.f;
  for (int n = lo2 + r; n < hi2; n += 4) acc += out2[(long)n * OUTF + c];
  __shared__ float s[256];
  s[threadIdx.x] = acc;
  __syncthreads();
  if (threadIdx.x < 64){
    float tot = s[c] + s[c + 64] + s[c + 128] + s[c + 192];
    int cnt = hi2 - lo2;
    out[g * OUTF + c] = (tot + (float)cnt * b2[c]) / fmaxf((float)cnt, 1.0f);
  }
}

extern "C" void kernel_launch(void* const* d_in, const int* in_sizes, int n_in,
                              void* d_out, int out_size, void* d_ws, size_t ws_size,
                              hipStream_t stream) {
  const float* x         = (const float*)d_in[0];
  const int*   eidx      = (const int*)d_in[1];
  const float* edge_attr = (const float*)d_in[2];
  const int*   batch     = (const int*)d_in[3];
  const float* W1        = (const float*)d_in[4];
  const float* att_src1  = (const float*)d_in[5];
  const float* att_dst1  = (const float*)d_in[6];
  const float* We1       = (const float*)d_in[7];
  const float* att_edge1 = (const float*)d_in[8];
  const float* b1        = (const float*)d_in[9];
  const float* W2        = (const float*)d_in[10];
  const float* att_src2  = (const float*)d_in[11];
  const float* att_dst2  = (const float*)d_in[12];
  const float* We2       = (const float*)d_in[13];
  const float* att_edge2 = (const float*)d_in[14];
  const float* b2        = (const float*)d_in[15];
  const int* srcI = eidx;
  const int* dstI = eidx + NE;

  float* ws = (float*)d_ws;
  float* h1     = ws;                       // NN*128 (reused as h2: NN*64)
  float* out1   = h1 + (long)NN * C1;       // NN*128 (reused as out2: NN*64)
  float* a_src1 = out1 + (long)NN * C1;     // NN*4 (reused as a_src2)
  float* a_dst1 = a_src1 + (long)NN * 4;    // NN*4 (reused as a_dst2)
  float* alpha1 = a_dst1 + (long)NN * 4;    // EP*4 (reused as alpha2: EP)
  float* m1     = alpha1 + (long)EP * 4;    // NN*4 (uint) (reused as m2: NN)
  float* denom1 = m1 + (long)NN * 4;        // NN*4 (reused as denom2: NN)
  float* sumEA  = denom1 + (long)NN * 4;    // 16
  float* meanEA = sumEA + 16;               // 16
  float* M1     = meanEA + 16;              // 64  [4][16]
  float* M2v    = M1 + 64;                  // 16
  float* aeSL1  = M2v + 16;                 // 4
  float* aeSL2  = aeSL1 + 4;                // 1
  // aliases for layer 2
  float* h2 = h1; float* out2 = out1;
  float* a_src2 = a_src1; float* a_dst2 = a_dst1;
  float* alpha2 = alpha1; float* m2 = m1; float* denom2 = denom1;

  // ---- prep ----
  hipMemsetAsync(sumEA, 0, 16 * sizeof(float), stream);
  hipMemsetAsync(m1, 0, (long)NN * 4 * sizeof(float), stream);
  hipMemsetAsync(denom1, 0, (long)NN * 4 * sizeof(float), stream);
  hipMemsetAsync(out1, 0, (long)NN * C1 * sizeof(float), stream);
  k_mean_ea<<<512, 256, 0, stream>>>(edge_attr, sumEA);
  k_prep<<<1, 128, 0, stream>>>(sumEA, We1, att_edge1, We2, att_edge2,
                                meanEA, M1, M2v, aeSL1, aeSL2);
  // ---- layer 1 ----
  k_gemm<<<dim3(cdiv(NN, 64), 2), 256, 0, stream>>>(x, W1, h1, NN, C1, 128);
  k_attdot1<<<cdiv((long)NN * 4, 256), 256, 0, stream>>>(h1, att_src1, att_dst1, a_src1, a_dst1);
  k_edgeA1<<<cdiv(EP, 256), 256, 0, stream>>>(srcI, dstI, edge_attr, M1, aeSL1,
                                              a_src1, a_dst1, alpha1, (unsigned*)m1);
  k_edgeB1<<<cdiv(EP, 256), 256, 0, stream>>>(dstI, alpha1, (unsigned*)m1, denom1);
  k_edgeC1<<<cdiv((long)EP * 32, 256), 256, 0, stream>>>(srcI, dstI, h1, alpha1, denom1, out1);
  k_elu<<<cdiv((long)NN * C1, 256), 256, 0, stream>>>(out1, b1);
  // ---- layer 2 ----
  k_gemm<<<dim3(cdiv(NN, 64), 1), 256, 0, stream>>>(out1, W2, h2, NN, OUTF, 128);
  k_attdot2<<<cdiv(NN, 256), 256, 0, stream>>>(h2, att_src2, att_dst2, a_src2, a_dst2);
  hipMemsetAsync(m2, 0, (long)NN * sizeof(float), stream);
  hipMemsetAsync(denom2, 0, (long)NN * sizeof(float), stream);
  k_edgeA2<<<cdiv(EP, 256), 256, 0, stream>>>(srcI, dstI, edge_attr, M2v, aeSL2,
                                              a_src2, a_dst2, alpha2, (unsigned*)m2);
  k_edgeB2<<<cdiv(EP, 256), 256, 0, stream>>>(dstI, alpha2, (unsigned*)m2, denom2);
  hipMemsetAsync(out2, 0, (long)NN * OUTF * sizeof(float), stream);
  k_edgeC2<<<cdiv((long)EP * 16, 256), 256, 0, stream>>>(srcI, dstI, h2, alpha2, denom2, out2);
  // ---- pool ----
  k_pool<<<NG, 256, 0, stream>>>(out2, batch, b2, (float*)d_out);
}

// Round 2
// 617.121 us; speedup vs baseline: 4.5960x; 4.5960x over previous
//
#include <hip/hip_runtime.h>
#include <math.h>

#define NN 50000      // nodes
#define NE 800000     // edges (without self loops)
#define EDF 16        // edge feature dim
#define C1 128        // heads*hid layer1
#define HID 32
#define OUTF 64
#define NG 64
#define SLOPE 0.2f
#define NB 196        // scan blocks = cdiv(NN,256)

static inline int cdiv(long a, long b){ return (int)((a + b - 1) / b); }

__device__ __forceinline__ float lrelu(float x){ return x >= 0.f ? x : SLOPE * x; }

// ---- mean of edge_attr over rows ----
__global__ void k_mean_ea(const float* __restrict__ ea, float* __restrict__ sumEA){
  int c = threadIdx.x & 15;
  int r0 = threadIdx.x >> 4;
  float acc = 0.f;
  for (long r = (long)blockIdx.x * 16 + r0; r < NE; r += (long)gridDim.x * 16)
    acc += ea[r * EDF + c];
  __shared__ float s[256];
  s[threadIdx.x] = acc;
  __syncthreads();
  for (int stride = 128; stride >= 16; stride >>= 1){
    if (threadIdx.x < stride) s[threadIdx.x] += s[threadIdx.x + stride];
    __syncthreads();
  }
  if (threadIdx.x < 16) atomicAdd(&sumEA[c], s[threadIdx.x]);
}

// ---- tiny prep: meanEA, M1[4][16], M2[16], self-loop a_edge constants ----
__global__ void k_prep(const float* __restrict__ sumEA,
                       const float* __restrict__ We1, const float* __restrict__ att_e1,
                       const float* __restrict__ We2, const float* __restrict__ att_e2,
                       float* __restrict__ meanEA, float* __restrict__ M1,
                       float* __restrict__ M2, float* __restrict__ aeSL1,
                       float* __restrict__ aeSL2){
  int t = threadIdx.x; // 128 threads
  if (t < 16) meanEA[t] = sumEA[t] * (1.0f / NE);
  if (t < 64){
    int h = t >> 4, d = t & 15;
    float s = 0.f;
    for (int c = 0; c < HID; c++) s += We1[d * C1 + h * HID + c] * att_e1[h * HID + c];
    M1[h * 16 + d] = s;
  }
  if (t >= 64 && t < 80){
    int d = t - 64;
    float s = 0.f;
    for (int c = 0; c < OUTF; c++) s += We2[d * OUTF + c] * att_e2[c];
    M2[d] = s;
  }
  __syncthreads();
  if (t < 4){
    float s = 0.f;
    for (int d = 0; d < 16; d++) s += meanEA[d] * M1[t * 16 + d];
    aeSL1[t] = s;
  }
  if (t == 4){
    float s = 0.f;
    for (int d = 0; d < 16; d++) s += meanEA[d] * M2[d];
    *aeSL2 = s;
  }
}

// ---- CSR build: histogram of dst ----
__global__ void k_hist(const int* __restrict__ dst, int* __restrict__ deg){
  long e = (long)blockIdx.x * blockDim.x + threadIdx.x;
  if (e < NE) atomicAdd(&deg[dst[e]], 1);
}

// ---- scan step 1: per-block exclusive scan + block totals ----
__global__ void k_scan1(const int* __restrict__ deg, int* __restrict__ rowStart,
                        int* __restrict__ blockSums){
  __shared__ int sd[256];
  int t = threadIdx.x;
  int i = blockIdx.x * 256 + t;
  int v = (i < NN) ? deg[i] : 0;
  sd[t] = v;
  __syncthreads();
  for (int off = 1; off < 256; off <<= 1){
    int add = (t >= off) ? sd[t - off] : 0;
    __syncthreads();
    sd[t] += add;
    __syncthreads();
  }
  int incl = sd[t];
  if (i < NN) rowStart[i] = incl - v;
  if (t == 255) blockSums[blockIdx.x] = incl;
}

// ---- scan step 2: exclusive scan of block totals (single block) ----
__global__ void k_scan2(int* __restrict__ blockSums){
  __shared__ int sd[256];
  int t = threadIdx.x;
  int v = (t < NB) ? blockSums[t] : 0;
  sd[t] = v;
  __syncthreads();
  for (int off = 1; off < 256; off <<= 1){
    int add = (t >= off) ? sd[t - off] : 0;
    __syncthreads();
    sd[t] += add;
    __syncthreads();
  }
  if (t < NB) blockSums[t] = sd[t] - v;
}

// ---- scan step 3: add block offsets; set rowStart[NN] ----
__global__ void k_scan3(int* __restrict__ rowStart, const int* __restrict__ blockSums){
  int i = blockIdx.x * 256 + threadIdx.x;
  if (i < NN) rowStart[i] += blockSums[blockIdx.x];
  if (i == 0) rowStart[NN] = NE;
}

// ---- scatter edges into dst-sorted order; precompute ae1[4], ae2 ----
__global__ void k_scatter(const int* __restrict__ src, const int* __restrict__ dst,
                          const float* __restrict__ ea,
                          const int* __restrict__ rowStart, int* __restrict__ cnt,
                          const float* __restrict__ M1, const float* __restrict__ M2,
                          unsigned short* __restrict__ srcC,
                          float* __restrict__ ae1C, float* __restrict__ ae2C){
  __shared__ float sM1[64];
  __shared__ float sM2[16];
  int t = threadIdx.x;
  if (t < 64) sM1[t] = M1[t];
  if (t < 16) sM2[t] = M2[t];
  __syncthreads();
  long e = (long)blockIdx.x * blockDim.x + t;
  if (e >= NE) return;
  int d = dst[e];
  int s = src[e];
  int pos = rowStart[d] + atomicAdd(&cnt[d], 1);
  float eav[16];
  const float4* p = (const float4*)(ea + e * EDF);
  *(float4*)&eav[0]  = p[0]; *(float4*)&eav[4]  = p[1];
  *(float4*)&eav[8]  = p[2]; *(float4*)&eav[12] = p[3];
  float ae[4];
#pragma unroll
  for (int h = 0; h < 4; h++){
    float sdot = 0.f;
#pragma unroll
    for (int dd = 0; dd < 16; dd++) sdot += eav[dd] * sM1[h * 16 + dd];
    ae[h] = sdot;
  }
  float a2 = 0.f;
#pragma unroll
  for (int dd = 0; dd < 16; dd++) a2 += eav[dd] * sM2[dd];
  srcC[pos] = (unsigned short)s;
  *(float4*)&ae1C[(long)pos * 4] = make_float4(ae[0], ae[1], ae[2], ae[3]);
  ae2C[pos] = a2;
}

// ---- f32 GEMM: C[M,Ncols] = A[M,K] @ B[K,Ncols]; BM=BN=64, BK=16, 256 thr ----
__global__ __launch_bounds__(256) void k_gemm(const float* __restrict__ A,
                                              const float* __restrict__ B,
                                              float* __restrict__ C,
                                              int M, int Ncols, int K){
  __shared__ float As[16][64];
  __shared__ float Bs[16][64];
  int tid = threadIdx.x;
  int row0 = blockIdx.x * 64, col0 = blockIdx.y * 64;
  int tx = tid & 15, ty = tid >> 4;
  int lrow = tid >> 2, lkq = tid & 3;
  int bk = tid >> 4, bc = tid & 15;
  float acc[4][4] = {};
  for (int k0 = 0; k0 < K; k0 += 16){
    float4 a4 = make_float4(0.f, 0.f, 0.f, 0.f);
    int gr = row0 + lrow;
    if (gr < M) a4 = *(const float4*)&A[(long)gr * K + k0 + lkq * 4];
    As[lkq * 4 + 0][lrow] = a4.x; As[lkq * 4 + 1][lrow] = a4.y;
    As[lkq * 4 + 2][lrow] = a4.z; As[lkq * 4 + 3][lrow] = a4.w;
    *(float4*)&Bs[bk][bc * 4] = *(const float4*)&B[(long)(k0 + bk) * Ncols + col0 + bc * 4];
    __syncthreads();
#pragma unroll
    for (int k = 0; k < 16; k++){
      float4 a = *(float4*)&As[k][ty * 4];
      float4 b = *(float4*)&Bs[k][tx * 4];
      acc[0][0] += a.x*b.x; acc[0][1] += a.x*b.y; acc[0][2] += a.x*b.z; acc[0][3] += a.x*b.w;
      acc[1][0] += a.y*b.x; acc[1][1] += a.y*b.y; acc[1][2] += a.y*b.z; acc[1][3] += a.y*b.w;
      acc[2][0] += a.z*b.x; acc[2][1] += a.z*b.y; acc[2][2] += a.z*b.z; acc[2][3] += a.z*b.w;
      acc[3][0] += a.w*b.x; acc[3][1] += a.w*b.y; acc[3][2] += a.w*b.z; acc[3][3] += a.w*b.w;
    }
    __syncthreads();
  }
#pragma unroll
  for (int i = 0; i < 4; i++){
    int r = row0 + ty * 4 + i;
    if (r < M){
      float4 v = make_float4(acc[i][0], acc[i][1], acc[i][2], acc[i][3]);
      *(float4*)&C[(long)r * Ncols + col0 + tx * 4] = v;
    }
  }
}

// ---- layer1 attention dots ----
__global__ void k_attdot1(const float* __restrict__ h1, const float* __restrict__ att_src,
                          const float* __restrict__ att_dst,
                          float* __restrict__ a_src, float* __restrict__ a_dst){
  long idx = (long)blockIdx.x * blockDim.x + threadIdx.x;
  if (idx >= (long)NN * 4) return;
  int h = (int)(idx & 3); long n = idx >> 2;
  const float* hp = h1 + n * C1 + h * HID;
  float ss = 0.f, sd = 0.f;
#pragma unroll
  for (int i = 0; i < HID; i += 4){
    float4 v = *(const float4*)&hp[i];
    float4 as = *(const float4*)&att_src[h * HID + i];
    float4 ad = *(const float4*)&att_dst[h * HID + i];
    ss += v.x*as.x + v.y*as.y + v.z*as.z + v.w*as.w;
    sd += v.x*ad.x + v.y*ad.y + v.z*ad.z + v.w*ad.w;
  }
  a_src[idx] = ss; a_dst[idx] = sd;
}

// ---- layer1 aggregation: one wave per dst node, atomic-free ----
__global__ __launch_bounds__(256) void k_agg1(
    const int* __restrict__ rowStart, const unsigned short* __restrict__ srcC,
    const float* __restrict__ ae1C, const float* __restrict__ a_src,
    const float* __restrict__ a_dst, const float* __restrict__ aeSL1,
    const float* __restrict__ h1, const float* __restrict__ b1,
    float* __restrict__ out1){
  int n = blockIdx.x * 4 + (threadIdx.x >> 6);
  int lane = threadIdx.x & 63;
  int start = rowStart[n];
  int dg = rowStart[n + 1] - start;
  float4 adN = *(const float4*)(a_dst + (long)n * 4);
  float4 asN = *(const float4*)(a_src + (long)n * 4);
  float4 sl  = *(const float4*)aeSL1;
  float4 aSelf = make_float4(lrelu(asN.x + adN.x + sl.x), lrelu(asN.y + adN.y + sl.y),
                             lrelu(asN.z + adN.z + sl.z), lrelu(asN.w + adN.w + sl.w));
  // pass 1: per-head max over edges (lane-strided) incl. self loop
  float4 m = aSelf;
  for (int j = lane; j < dg; j += 64){
    int s = srcC[start + j];
    float4 as = *(const float4*)(a_src + (long)s * 4);
    float4 ae = *(const float4*)(ae1C + (long)(start + j) * 4);
    m.x = fmaxf(m.x, lrelu(as.x + adN.x + ae.x));
    m.y = fmaxf(m.y, lrelu(as.y + adN.y + ae.y));
    m.z = fmaxf(m.z, lrelu(as.z + adN.z + ae.z));
    m.w = fmaxf(m.w, lrelu(as.w + adN.w + ae.w));
  }
#pragma unroll
  for (int off = 32; off > 0; off >>= 1){
    m.x = fmaxf(m.x, __shfl_xor(m.x, off));
    m.y = fmaxf(m.y, __shfl_xor(m.y, off));
    m.z = fmaxf(m.z, __shfl_xor(m.z, off));
    m.w = fmaxf(m.w, __shfl_xor(m.w, off));
  }
  // pass 2: edge-serial, channel-parallel (2 ch/lane, same head)
  int ch = lane * 2;
  int h = lane >> 4;
  float mh = ((const float*)&m)[h];
  float adh = ((const float*)&adN)[h];
  float cSelf = expf(((const float*)&aSelf)[h] - mh);
  float denom = cSelf;
  float2 hv0 = *(const float2*)(h1 + (long)n * C1 + ch);
  float acc0 = hv0.x * cSelf, acc1 = hv0.y * cSelf;
  int sj = 0; float aej = 0.f;
  if (dg > 0){ sj = srcC[start]; aej = ae1C[(long)start * 4 + h]; }
  for (int j = 0; j < dg; j++){
    int sn = 0; float aen = 0.f;
    if (j + 1 < dg){ sn = srcC[start + j + 1]; aen = ae1C[(long)(start + j + 1) * 4 + h]; }
    float al = lrelu(a_src[(long)sj * 4 + h] + adh + aej);
    float c = expf(al - mh);
    denom += c;
    float2 hv = *(const float2*)(h1 + (long)sj * C1 + ch);
    acc0 += hv.x * c; acc1 += hv.y * c;
    sj = sn; aej = aen;
  }
  float inv = 1.f / (denom + 1e-16f);
  float v0 = acc0 * inv + b1[ch];
  float v1 = acc1 * inv + b1[ch + 1];
  out1[(long)n * C1 + ch]     = v0 > 0.f ? v0 : expf(v0) - 1.f;
  out1[(long)n * C1 + ch + 1] = v1 > 0.f ? v1 : expf(v1) - 1.f;
}

// ---- layer2 attention dots (1 head, 64 ch) ----
__global__ void k_attdot2(const float* __restrict__ h2, const float* __restrict__ att_src,
                          const float* __restrict__ att_dst,
                          float* __restrict__ a_src, float* __restrict__ a_dst){
  long n = (long)blockIdx.x * blockDim.x + threadIdx.x;
  if (n >= NN) return;
  const float* hp = h2 + n * OUTF;
  float ss = 0.f, sd = 0.f;
#pragma unroll
  for (int i = 0; i < OUTF; i += 4){
    float4 v = *(const float4*)&hp[i];
    float4 as = *(const float4*)&att_src[i];
    float4 ad = *(const float4*)&att_dst[i];
    ss += v.x*as.x + v.y*as.y + v.z*as.z + v.w*as.w;
    sd += v.x*ad.x + v.y*ad.y + v.z*ad.z + v.w*ad.w;
  }
  a_src[n] = ss; a_dst[n] = sd;
}

// ---- layer2 aggregation: one wave per node ----
__global__ __launch_bounds__(256) void k_agg2(
    const int* __restrict__ rowStart, const unsigned short* __restrict__ srcC,
    const float* __restrict__ ae2C, const float* __restrict__ a_src,
    const float* __restrict__ a_dst, const float* __restrict__ aeSL2,
    const float* __restrict__ h2, float* __restrict__ out2){
  int n = blockIdx.x * 4 + (threadIdx.x >> 6);
  int lane = threadIdx.x & 63;
  int start = rowStart[n];
  int dg = rowStart[n + 1] - start;
  float adN = a_dst[n];
  float aSelf = lrelu(a_src[n] + adN + *aeSL2);
  float m = aSelf;
  for (int j = lane; j < dg; j += 64){
    int s = srcC[start + j];
    m = fmaxf(m, lrelu(a_src[s] + adN + ae2C[start + j]));
  }
#pragma unroll
  for (int off = 32; off > 0; off >>= 1) m = fmaxf(m, __shfl_xor(m, off));
  float cSelf = expf(aSelf - m);
  float denom = cSelf;
  float acc = h2[(long)n * OUTF + lane] * cSelf;
  int sj = 0; float aej = 0.f;
  if (dg > 0){ sj = srcC[start]; aej = ae2C[start]; }
  for (int j = 0; j < dg; j++){
    int sn = 0; float aen = 0.f;
    if (j + 1 < dg){ sn = srcC[start + j + 1]; aen = ae2C[start + j + 1]; }
    float al = lrelu(a_src[sj] + adN + aej);
    float c = expf(al - m);
    denom += c;
    acc += h2[(long)sj * OUTF + lane] * c;
    sj = sn; aej = aen;
  }
  out2[(long)n * OUTF + lane] = acc / (denom + 1e-16f);
}

// ---- pool ----
__global__ void k_pool(const float* __restrict__ out2, const int* __restrict__ batch,
                       const float* __restrict__ b2, float* __restrict__ out){
  int g = blockIdx.x;
  int lo = 0, hi = NN;
  while (lo < hi){ int mid = (lo + hi) >> 1; if (batch[mid] < g) lo = mid + 1; else hi = mid; }
  int lo2 = lo;
  int a = lo, b = NN;
  while (a < b){ int mid = (a + b) >> 1; if (batch[mid] < g + 1) a = mid + 1; else b = mid; }
  int hi2 = a;
  int c = threadIdx.x & 63, r = threadIdx.x >> 6;
  float acc = 0.f;
  for (int n = lo2 + r; n < hi2; n += 4) acc += out2[(long)n * OUTF + c];
  __shared__ float s[256];
  s[threadIdx.x] = acc;
  __syncthreads();
  if (threadIdx.x < 64){
    float tot = s[c] + s[c + 64] + s[c + 128] + s[c + 192];
    int cnt = hi2 - lo2;
    out[g * OUTF + c] = (tot + (float)cnt * b2[c]) / fmaxf((float)cnt, 1.0f);
  }
}

extern "C" void kernel_launch(void* const* d_in, const int* in_sizes, int n_in,
                              void* d_out, int out_size, void* d_ws, size_t ws_size,
                              hipStream_t stream) {
  const float* x         = (const float*)d_in[0];
  const int*   eidx      = (const int*)d_in[1];
  const float* edge_attr = (const float*)d_in[2];
  const int*   batch     = (const int*)d_in[3];
  const float* W1        = (const float*)d_in[4];
  const float* att_src1  = (const float*)d_in[5];
  const float* att_dst1  = (const float*)d_in[6];
  const float* We1       = (const float*)d_in[7];
  const float* att_edge1 = (const float*)d_in[8];
  const float* b1        = (const float*)d_in[9];
  const float* W2        = (const float*)d_in[10];
  const float* att_src2  = (const float*)d_in[11];
  const float* att_dst2  = (const float*)d_in[12];
  const float* We2       = (const float*)d_in[13];
  const float* att_edge2 = (const float*)d_in[14];
  const float* b2        = (const float*)d_in[15];
  const int* srcI = eidx;
  const int* dstI = eidx + NE;

  float* ws = (float*)d_ws;
  float* h1     = ws;                        // NN*128 (reused as h2: NN*64)
  float* out1   = h1 + (long)NN * C1;        // NN*128 (reused as out2: NN*64)
  float* a_src1 = out1 + (long)NN * C1;      // NN*4 (layer2 reuses as NN)
  float* a_dst1 = a_src1 + (long)NN * 4;     // NN*4
  float* ae1C   = a_dst1 + (long)NN * 4;     // NE*4
  float* ae2C   = ae1C + (long)NE * 4;       // NE
  int*   deg    = (int*)(ae2C + NE);         // NN
  int*   rowStart = deg + NN;                // NN+1
  int*   cnt    = rowStart + NN + 1;         // NN
  int*   blockSums = cnt + NN;               // 256
  unsigned short* srcC = (unsigned short*)(blockSums + 256); // NE
  float* sumEA  = (float*)(srcC + NE);       // 16
  float* meanEA = sumEA + 16;                // 16
  float* M1     = meanEA + 16;               // 64
  float* M2v    = M1 + 64;                   // 16
  float* aeSL1  = M2v + 16;                  // 4
  float* aeSL2  = aeSL1 + 4;                 // 4
  float* h2 = h1; float* out2 = out1;
  float* a_src2 = a_src1; float* a_dst2 = a_dst1;

  // ---- prep + CSR build ----
  hipMemsetAsync(sumEA, 0, 16 * sizeof(float), stream);
  hipMemsetAsync(deg, 0, NN * sizeof(int), stream);
  hipMemsetAsync(cnt, 0, NN * sizeof(int), stream);
  k_mean_ea<<<512, 256, 0, stream>>>(edge_attr, sumEA);
  k_prep<<<1, 128, 0, stream>>>(sumEA, We1, att_edge1, We2, att_edge2,
                                meanEA, M1, M2v, aeSL1, aeSL2);
  k_hist<<<cdiv(NE, 256), 256, 0, stream>>>(dstI, deg);
  k_scan1<<<NB, 256, 0, stream>>>(deg, rowStart, blockSums);
  k_scan2<<<1, 256, 0, stream>>>(blockSums);
  k_scan3<<<NB, 256, 0, stream>>>(rowStart, blockSums);
  k_scatter<<<cdiv(NE, 256), 256, 0, stream>>>(srcI, dstI, edge_attr, rowStart, cnt,
                                               M1, M2v, srcC, ae1C, ae2C);
  // ---- layer 1 ----
  k_gemm<<<dim3(cdiv(NN, 64), 2), 256, 0, stream>>>(x, W1, h1, NN, C1, 128);
  k_attdot1<<<cdiv((long)NN * 4, 256), 256, 0, stream>>>(h1, att_src1, att_dst1, a_src1, a_dst1);
  k_agg1<<<NN / 4, 256, 0, stream>>>(rowStart, srcC, ae1C, a_src1, a_dst1, aeSL1,
                                     h1, b1, out1);
  // ---- layer 2 ----
  k_gemm<<<dim3(cdiv(NN, 64), 1), 256, 0, stream>>>(out1, W2, h2, NN, OUTF, 128);
  k_attdot2<<<cdiv(NN, 256), 256, 0, stream>>>(h2, att_src2, att_dst2, a_src2, a_dst2);
  k_agg2<<<NN / 4, 256, 0, stream>>>(rowStart, srcC, ae2C, a_src2, a_dst2, aeSL2,
                                     h2, out2);
  // ---- pool ----
  k_pool<<<NG, 256, 0, stream>>>(out2, batch, b2, (float*)d_out);
}

// Round 4
// 464.010 us; speedup vs baseline: 6.1126x; 1.3300x over previous
//
#include <hip/hip_runtime.h>
#include <hip/hip_fp16.h>
#include <math.h>

#define NN 50000      // nodes
#define NE 800000     // edges (without self loops)
#define EDF 16        // edge feature dim
#define C1 128        // heads*hid layer1
#define HID 32
#define OUTF 64
#define NG 64
#define SLOPE 0.2f
#define NB 196        // scan blocks = cdiv(NN,256)
#define MAXE 256      // LDS-cached edges per node (fallback path beyond)

static inline int cdiv(long a, long b){ return (int)((a + b - 1) / b); }

__device__ __forceinline__ float lrelu(float x){ return x >= 0.f ? x : SLOPE * x; }

// ---- mean of edge_attr over rows ----
__global__ void k_mean_ea(const float* __restrict__ ea, float* __restrict__ sumEA){
  int c = threadIdx.x & 15;
  int r0 = threadIdx.x >> 4;
  float acc = 0.f;
  for (long r = (long)blockIdx.x * 16 + r0; r < NE; r += (long)gridDim.x * 16)
    acc += ea[r * EDF + c];
  __shared__ float s[256];
  s[threadIdx.x] = acc;
  __syncthreads();
  for (int stride = 128; stride >= 16; stride >>= 1){
    if (threadIdx.x < stride) s[threadIdx.x] += s[threadIdx.x + stride];
    __syncthreads();
  }
  if (threadIdx.x < 16) atomicAdd(&sumEA[c], s[threadIdx.x]);
}

// ---- tiny prep: meanEA, M1[4][16], M2[16], self-loop a_edge constants ----
__global__ void k_prep(const float* __restrict__ sumEA,
                       const float* __restrict__ We1, const float* __restrict__ att_e1,
                       const float* __restrict__ We2, const float* __restrict__ att_e2,
                       float* __restrict__ meanEA, float* __restrict__ M1,
                       float* __restrict__ M2, float* __restrict__ aeSL1,
                       float* __restrict__ aeSL2){
  int t = threadIdx.x; // 128 threads
  if (t < 16) meanEA[t] = sumEA[t] * (1.0f / NE);
  if (t < 64){
    int h = t >> 4, d = t & 15;
    float s = 0.f;
    for (int c = 0; c < HID; c++) s += We1[d * C1 + h * HID + c] * att_e1[h * HID + c];
    M1[h * 16 + d] = s;
  }
  if (t >= 64 && t < 80){
    int d = t - 64;
    float s = 0.f;
    for (int c = 0; c < OUTF; c++) s += We2[d * OUTF + c] * att_e2[c];
    M2[d] = s;
  }
  __syncthreads();
  if (t < 4){
    float s = 0.f;
    for (int d = 0; d < 16; d++) s += meanEA[d] * M1[t * 16 + d];
    aeSL1[t] = s;
  }
  if (t == 4){
    float s = 0.f;
    for (int d = 0; d < 16; d++) s += meanEA[d] * M2[d];
    *aeSL2 = s;
  }
}

// ---- CSR build: histogram of dst ----
__global__ void k_hist(const int* __restrict__ dst, int* __restrict__ deg){
  long e = (long)blockIdx.x * blockDim.x + threadIdx.x;
  if (e < NE) atomicAdd(&deg[dst[e]], 1);
}

// ---- scan step 1 ----
__global__ void k_scan1(const int* __restrict__ deg, int* __restrict__ rowStart,
                        int* __restrict__ blockSums){
  __shared__ int sd[256];
  int t = threadIdx.x;
  int i = blockIdx.x * 256 + t;
  int v = (i < NN) ? deg[i] : 0;
  sd[t] = v;
  __syncthreads();
  for (int off = 1; off < 256; off <<= 1){
    int add = (t >= off) ? sd[t - off] : 0;
    __syncthreads();
    sd[t] += add;
    __syncthreads();
  }
  int incl = sd[t];
  if (i < NN) rowStart[i] = incl - v;
  if (t == 255) blockSums[blockIdx.x] = incl;
}

// ---- scan step 2 ----
__global__ void k_scan2(int* __restrict__ blockSums){
  __shared__ int sd[256];
  int t = threadIdx.x;
  int v = (t < NB) ? blockSums[t] : 0;
  sd[t] = v;
  __syncthreads();
  for (int off = 1; off < 256; off <<= 1){
    int add = (t >= off) ? sd[t - off] : 0;
    __syncthreads();
    sd[t] += add;
    __syncthreads();
  }
  if (t < NB) blockSums[t] = sd[t] - v;
}

// ---- scan step 3 ----
__global__ void k_scan3(int* __restrict__ rowStart, const int* __restrict__ blockSums){
  int i = blockIdx.x * 256 + threadIdx.x;
  if (i < NN) rowStart[i] += blockSums[blockIdx.x];
  if (i == 0) rowStart[NN] = NE;
}

// ---- scatter edges into dst-sorted order; precompute ae1[4], ae2 ----
__global__ void k_scatter(const int* __restrict__ src, const int* __restrict__ dst,
                          const float* __restrict__ ea,
                          const int* __restrict__ rowStart, int* __restrict__ cnt,
                          const float* __restrict__ M1, const float* __restrict__ M2,
                          unsigned short* __restrict__ srcC,
                          float* __restrict__ ae1C, float* __restrict__ ae2C){
  __shared__ float sM1[64];
  __shared__ float sM2[16];
  int t = threadIdx.x;
  if (t < 64) sM1[t] = M1[t];
  if (t < 16) sM2[t] = M2[t];
  __syncthreads();
  long e = (long)blockIdx.x * blockDim.x + t;
  if (e >= NE) return;
  int d = dst[e];
  int s = src[e];
  int pos = rowStart[d] + atomicAdd(&cnt[d], 1);
  float eav[16];
  const float4* p = (const float4*)(ea + e * EDF);
  *(float4*)&eav[0]  = p[0]; *(float4*)&eav[4]  = p[1];
  *(float4*)&eav[8]  = p[2]; *(float4*)&eav[12] = p[3];
  float ae[4];
#pragma unroll
  for (int h = 0; h < 4; h++){
    float sdot = 0.f;
#pragma unroll
    for (int dd = 0; dd < 16; dd++) sdot += eav[dd] * sM1[h * 16 + dd];
    ae[h] = sdot;
  }
  float a2 = 0.f;
#pragma unroll
  for (int dd = 0; dd < 16; dd++) a2 += eav[dd] * sM2[dd];
  srcC[pos] = (unsigned short)s;
  *(float4*)&ae1C[(long)pos * 4] = make_float4(ae[0], ae[1], ae[2], ae[3]);
  ae2C[pos] = a2;
}

// ---- f32 GEMM writing fp16: Ch[M,Ncols] = A[M,K] @ B[K,Ncols] ----
__global__ __launch_bounds__(256) void k_gemm(const float* __restrict__ A,
                                              const float* __restrict__ B,
                                              __half* __restrict__ Ch,
                                              int M, int Ncols, int K){
  __shared__ float As[16][64];
  __shared__ float Bs[16][64];
  int tid = threadIdx.x;
  int row0 = blockIdx.x * 64, col0 = blockIdx.y * 64;
  int tx = tid & 15, ty = tid >> 4;
  int lrow = tid >> 2, lkq = tid & 3;
  int bk = tid >> 4, bc = tid & 15;
  float acc[4][4] = {};
  for (int k0 = 0; k0 < K; k0 += 16){
    float4 a4 = make_float4(0.f, 0.f, 0.f, 0.f);
    int gr = row0 + lrow;
    if (gr < M) a4 = *(const float4*)&A[(long)gr * K + k0 + lkq * 4];
    As[lkq * 4 + 0][lrow] = a4.x; As[lkq * 4 + 1][lrow] = a4.y;
    As[lkq * 4 + 2][lrow] = a4.z; As[lkq * 4 + 3][lrow] = a4.w;
    *(float4*)&Bs[bk][bc * 4] = *(const float4*)&B[(long)(k0 + bk) * Ncols + col0 + bc * 4];
    __syncthreads();
#pragma unroll
    for (int k = 0; k < 16; k++){
      float4 a = *(float4*)&As[k][ty * 4];
      float4 b = *(float4*)&Bs[k][tx * 4];
      acc[0][0] += a.x*b.x; acc[0][1] += a.x*b.y; acc[0][2] += a.x*b.z; acc[0][3] += a.x*b.w;
      acc[1][0] += a.y*b.x; acc[1][1] += a.y*b.y; acc[1][2] += a.y*b.z; acc[1][3] += a.y*b.w;
      acc[2][0] += a.z*b.x; acc[2][1] += a.z*b.y; acc[2][2] += a.z*b.z; acc[2][3] += a.z*b.w;
      acc[3][0] += a.w*b.x; acc[3][1] += a.w*b.y; acc[3][2] += a.w*b.z; acc[3][3] += a.w*b.w;
    }
    __syncthreads();
  }
#pragma unroll
  for (int i = 0; i < 4; i++){
    int r = row0 + ty * 4 + i;
    if (r < M){
      __half2 p0 = __floats2half2_rn(acc[i][0], acc[i][1]);
      __half2 p1 = __floats2half2_rn(acc[i][2], acc[i][3]);
      uint2 pk;
      pk.x = *(unsigned int*)&p0;
      pk.y = *(unsigned int*)&p1;
      *(uint2*)&Ch[(long)r * Ncols + col0 + tx * 4] = pk;
    }
  }
}

// ---- layer1 attention dots (fp16 h) ----
__global__ void k_attdot1(const __half* __restrict__ h1h, const float* __restrict__ att_src,
                          const float* __restrict__ att_dst,
                          float* __restrict__ a_src, float* __restrict__ a_dst){
  long idx = (long)blockIdx.x * blockDim.x + threadIdx.x;
  if (idx >= (long)NN * 4) return;
  int h = (int)(idx & 3); long n = idx >> 2;
  const unsigned int* hp = (const unsigned int*)h1h + n * 64 + h * 16;
  float ss = 0.f, sd = 0.f;
#pragma unroll
  for (int i = 0; i < 16; i++){
    unsigned int u = hp[i];
    float2 f = __half22float2(*(__half2*)&u);
    ss += f.x * att_src[h * HID + 2*i] + f.y * att_src[h * HID + 2*i + 1];
    sd += f.x * att_dst[h * HID + 2*i] + f.y * att_dst[h * HID + 2*i + 1];
  }
  a_src[idx] = ss; a_dst[idx] = sd;
}

// ---- layer1 aggregation: 1 wave/node, lane-parallel softmax, fp16 gather ----
__global__ __launch_bounds__(256) void k_agg1(
    const int* __restrict__ rowStart, const unsigned short* __restrict__ srcC,
    const float* __restrict__ ae1C, const float* __restrict__ a_src,
    const float* __restrict__ a_dst, const float* __restrict__ aeSL1,
    const __half* __restrict__ h1h, const float* __restrict__ b1,
    float* __restrict__ out1){
  __shared__ int   sS[4][MAXE];
  __shared__ float sC[4][MAXE * 4];
  int wid = threadIdx.x >> 6;
  int lane = threadIdx.x & 63;
  int n = blockIdx.x * 4 + wid;
  int start = rowStart[n];
  int dg = rowStart[n + 1] - start;
  float4 ad4 = *(const float4*)(a_dst + (long)n * 4);
  float4 as4 = *(const float4*)(a_src + (long)n * 4);
  float4 sl4 = *(const float4*)aeSL1;
  float4 aSelf;
  aSelf.x = lrelu(as4.x + ad4.x + sl4.x);
  aSelf.y = lrelu(as4.y + ad4.y + sl4.y);
  aSelf.z = lrelu(as4.z + ad4.z + sl4.z);
  aSelf.w = lrelu(as4.w + ad4.w + sl4.w);
  // phase A: lane-parallel alphas; chunk0 kept in registers, others in LDS
  float4 m = aSelf;
  float4 al0 = make_float4(0.f, 0.f, 0.f, 0.f);
  for (int j0 = 0; j0 < dg; j0 += 64){
    int j = j0 + lane;
    if (j < dg){
      int s = srcC[start + j];
      float4 asv = *(const float4*)(a_src + (long)s * 4);
      float4 ae = *(const float4*)(ae1C + (long)(start + j) * 4);
      float4 al;
      al.x = lrelu(asv.x + ad4.x + ae.x);
      al.y = lrelu(asv.y + ad4.y + ae.y);
      al.z = lrelu(asv.z + ad4.z + ae.z);
      al.w = lrelu(asv.w + ad4.w + ae.w);
      m.x = fmaxf(m.x, al.x); m.y = fmaxf(m.y, al.y);
      m.z = fmaxf(m.z, al.z); m.w = fmaxf(m.w, al.w);
      if (j < MAXE) sS[wid][j] = s;
      if (j0 == 0) al0 = al;
      else if (j < MAXE) *(float4*)&sC[wid][j * 4] = al;
    }
  }
#pragma unroll
  for (int off = 32; off > 0; off >>= 1){
    m.x = fmaxf(m.x, __shfl_xor(m.x, off));
    m.y = fmaxf(m.y, __shfl_xor(m.y, off));
    m.z = fmaxf(m.z, __shfl_xor(m.z, off));
    m.w = fmaxf(m.w, __shfl_xor(m.w, off));
  }
  // phase B: c = exp(al - m), denominator partials, write c to LDS
  float4 dsum = make_float4(0.f, 0.f, 0.f, 0.f);
  for (int j0 = 0; j0 < dg; j0 += 64){
    int j = j0 + lane;
    if (j < dg){
      float4 al;
      if (j0 == 0) al = al0;
      else if (j < MAXE) al = *(float4*)&sC[wid][j * 4];
      else {
        int s = srcC[start + j];
        float4 asv = *(const float4*)(a_src + (long)s * 4);
        float4 ae = *(const float4*)(ae1C + (long)(start + j) * 4);
        al.x = lrelu(asv.x + ad4.x + ae.x);
        al.y = lrelu(asv.y + ad4.y + ae.y);
        al.z = lrelu(asv.z + ad4.z + ae.z);
        al.w = lrelu(asv.w + ad4.w + ae.w);
      }
      float4 c;
      c.x = expf(al.x - m.x); c.y = expf(al.y - m.y);
      c.z = expf(al.z - m.z); c.w = expf(al.w - m.w);
      dsum.x += c.x; dsum.y += c.y; dsum.z += c.z; dsum.w += c.w;
      if (j < MAXE) *(float4*)&sC[wid][j * 4] = c;
    }
  }
#pragma unroll
  for (int off = 32; off > 0; off >>= 1){
    dsum.x += __shfl_xor(dsum.x, off);
    dsum.y += __shfl_xor(dsum.y, off);
    dsum.z += __shfl_xor(dsum.z, off);
    dsum.w += __shfl_xor(dsum.w, off);
  }
  float4 cSelf;
  cSelf.x = expf(aSelf.x - m.x); cSelf.y = expf(aSelf.y - m.y);
  cSelf.z = expf(aSelf.z - m.z); cSelf.w = expf(aSelf.w - m.w);
  // Extract per-head scalars through REAL ARRAYS (defined behavior).
  // (&m.x)[h] is UB: SROA scalarizes float4 members and a variable GEP on a
  // scalar alloca is out-of-bounds -> poison for h>0 (round-3 failure mode).
  float mA[4]  = {m.x, m.y, m.z, m.w};
  float adA[4] = {ad4.x, ad4.y, ad4.z, ad4.w};
  float csA[4] = {cSelf.x, cSelf.y, cSelf.z, cSelf.w};
  float invA[4];
  invA[0] = 1.f / (dsum.x + cSelf.x + 1e-16f);
  invA[1] = 1.f / (dsum.y + cSelf.y + 1e-16f);
  invA[2] = 1.f / (dsum.z + cSelf.z + 1e-16f);
  invA[3] = 1.f / (dsum.w + cSelf.w + 1e-16f);
  // pass 2: channel-parallel weighted gather (2 ch/lane), unrolled x4
  int ch = lane * 2;
  int h = lane >> 4;
  const unsigned int* hrow = (const unsigned int*)h1h;
  float cs   = csA[h];
  float vinv = invA[h];
  float mh   = mA[h];
  float adh  = adA[h];
  unsigned int hv = hrow[(long)n * 64 + lane];
  float2 hf = __half22float2(*(__half2*)&hv);
  float acc0 = hf.x * cs, acc1 = hf.y * cs;
  int jmax = dg < MAXE ? dg : MAXE;
  int j = 0;
  for (; j + 4 <= jmax; j += 4){
    int s0 = sS[wid][j+0], s1 = sS[wid][j+1], s2 = sS[wid][j+2], s3 = sS[wid][j+3];
    float c0 = sC[wid][(j+0)*4+h], c1 = sC[wid][(j+1)*4+h];
    float c2 = sC[wid][(j+2)*4+h], c3 = sC[wid][(j+3)*4+h];
    unsigned int v0 = hrow[(long)s0 * 64 + lane];
    unsigned int v1 = hrow[(long)s1 * 64 + lane];
    unsigned int v2 = hrow[(long)s2 * 64 + lane];
    unsigned int v3 = hrow[(long)s3 * 64 + lane];
    float2 f0 = __half22float2(*(__half2*)&v0);
    float2 f1 = __half22float2(*(__half2*)&v1);
    float2 f2 = __half22float2(*(__half2*)&v2);
    float2 f3 = __half22float2(*(__half2*)&v3);
    acc0 += c0 * f0.x + c1 * f1.x + c2 * f2.x + c3 * f3.x;
    acc1 += c0 * f0.y + c1 * f1.y + c2 * f2.y + c3 * f3.y;
  }
  for (; j < jmax; j++){
    int s = sS[wid][j];
    float c = sC[wid][j * 4 + h];
    unsigned int v = hrow[(long)s * 64 + lane];
    float2 f = __half22float2(*(__half2*)&v);
    acc0 += c * f.x; acc1 += c * f.y;
  }
  for (; j < dg; j++){ // rare fallback (dg > MAXE)
    int s = srcC[start + j];
    float asv = a_src[(long)s * 4 + h];
    float ae = ae1C[(long)(start + j) * 4 + h];
    float c = expf(lrelu(asv + adh + ae) - mh);
    unsigned int v = hrow[(long)s * 64 + lane];
    float2 f = __half22float2(*(__half2*)&v);
    acc0 += c * f.x; acc1 += c * f.y;
  }
  float v0 = acc0 * vinv + b1[ch];
  float v1 = acc1 * vinv + b1[ch + 1];
  v0 = v0 > 0.f ? v0 : expf(v0) - 1.f;
  v1 = v1 > 0.f ? v1 : expf(v1) - 1.f;
  *(float2*)&out1[(long)n * C1 + ch] = make_float2(v0, v1);
}

// ---- layer2 attention dots (fp16 h, 1 head, 64 ch) ----
__global__ void k_attdot2(const __half* __restrict__ h2h, const float* __restrict__ att_src,
                          const float* __restrict__ att_dst,
                          float* __restrict__ a_src, float* __restrict__ a_dst){
  long n = (long)blockIdx.x * blockDim.x + threadIdx.x;
  if (n >= NN) return;
  const unsigned int* hp = (const unsigned int*)h2h + n * 32;
  float ss = 0.f, sd = 0.f;
#pragma unroll
  for (int i = 0; i < 32; i++){
    unsigned int u = hp[i];
    float2 f = __half22float2(*(__half2*)&u);
    ss += f.x * att_src[2*i] + f.y * att_src[2*i + 1];
    sd += f.x * att_dst[2*i] + f.y * att_dst[2*i + 1];
  }
  a_src[n] = ss; a_dst[n] = sd;
}

// ---- layer2 aggregation: 1 wave/node, fp16 gather ----
__global__ __launch_bounds__(256) void k_agg2(
    const int* __restrict__ rowStart, const unsigned short* __restrict__ srcC,
    const float* __restrict__ ae2C, const float* __restrict__ a_src,
    const float* __restrict__ a_dst, const float* __restrict__ aeSL2,
    const __half* __restrict__ h2h, float* __restrict__ out2){
  __shared__ int   sS[4][MAXE];
  __shared__ float sC[4][MAXE];
  int wid = threadIdx.x >> 6;
  int lane = threadIdx.x & 63;
  int n = blockIdx.x * 4 + wid;
  int start = rowStart[n];
  int dg = rowStart[n + 1] - start;
  float adN = a_dst[n];
  float aSelf = lrelu(a_src[n] + adN + *aeSL2);
  float m = aSelf;
  float al0 = 0.f;
  for (int j0 = 0; j0 < dg; j0 += 64){
    int j = j0 + lane;
    if (j < dg){
      int s = srcC[start + j];
      float al = lrelu(a_src[s] + adN + ae2C[start + j]);
      m = fmaxf(m, al);
      if (j < MAXE) sS[wid][j] = s;
      if (j0 == 0) al0 = al;
      else if (j < MAXE) sC[wid][j] = al;
    }
  }
#pragma unroll
  for (int off = 32; off > 0; off >>= 1) m = fmaxf(m, __shfl_xor(m, off));
  float dsum = 0.f;
  for (int j0 = 0; j0 < dg; j0 += 64){
    int j = j0 + lane;
    if (j < dg){
      float al;
      if (j0 == 0) al = al0;
      else if (j < MAXE) al = sC[wid][j];
      else { int s = srcC[start + j]; al = lrelu(a_src[s] + adN + ae2C[start + j]); }
      float c = expf(al - m);
      dsum += c;
      if (j < MAXE) sC[wid][j] = c;
    }
  }
#pragma unroll
  for (int off = 32; off > 0; off >>= 1) dsum += __shfl_xor(dsum, off);
  float cSelf = expf(aSelf - m);
  float inv = 1.f / (dsum + cSelf + 1e-16f);
  float acc = __half2float(h2h[(long)n * OUTF + lane]) * cSelf;
  int jmax = dg < MAXE ? dg : MAXE;
  int j = 0;
  for (; j + 4 <= jmax; j += 4){
    int s0 = sS[wid][j+0], s1 = sS[wid][j+1], s2 = sS[wid][j+2], s3 = sS[wid][j+3];
    float c0 = sC[wid][j+0], c1 = sC[wid][j+1], c2 = sC[wid][j+2], c3 = sC[wid][j+3];
    float f0 = __half2float(h2h[(long)s0 * OUTF + lane]);
    float f1 = __half2float(h2h[(long)s1 * OUTF + lane]);
    float f2 = __half2float(h2h[(long)s2 * OUTF + lane]);
    float f3 = __half2float(h2h[(long)s3 * OUTF + lane]);
    acc += c0 * f0 + c1 * f1 + c2 * f2 + c3 * f3;
  }
  for (; j < jmax; j++)
    acc += sC[wid][j] * __half2float(h2h[(long)sS[wid][j] * OUTF + lane]);
  for (; j < dg; j++){ // rare fallback
    int s = srcC[start + j];
    float c = expf(lrelu(a_src[s] + adN + ae2C[start + j]) - m);
    acc += c * __half2float(h2h[(long)s * OUTF + lane]);
  }
  out2[(long)n * OUTF + lane] = acc * inv;
}

// ---- pool ----
__global__ void k_pool(const float* __restrict__ out2, const int* __restrict__ batch,
                       const float* __restrict__ b2, float* __restrict__ out){
  int g = blockIdx.x;
  int lo = 0, hi = NN;
  while (lo < hi){ int mid = (lo + hi) >> 1; if (batch[mid] < g) lo = mid + 1; else hi = mid; }
  int lo2 = lo;
  int a = lo, b = NN;
  while (a < b){ int mid = (a + b) >> 1; if (batch[mid] < g + 1) a = mid + 1; else b = mid; }
  int hi2 = a;
  int c = threadIdx.x & 63, r = threadIdx.x >> 6;
  float acc = 0.f;
  for (int n = lo2 + r; n < hi2; n += 4) acc += out2[(long)n * OUTF + c];
  __shared__ float s[256];
  s[threadIdx.x] = acc;
  __syncthreads();
  if (threadIdx.x < 64){
    float tot = s[c] + s[c + 64] + s[c + 128] + s[c + 192];
    int cnt = hi2 - lo2;
    out[g * OUTF + c] = (tot + (float)cnt * b2[c]) / fmaxf((float)cnt, 1.0f);
  }
}

extern "C" void kernel_launch(void* const* d_in, const int* in_sizes, int n_in,
                              void* d_out, int out_size, void* d_ws, size_t ws_size,
                              hipStream_t stream) {
  const float* x         = (const float*)d_in[0];
  const int*   eidx      = (const int*)d_in[1];
  const float* edge_attr = (const float*)d_in[2];
  const int*   batch     = (const int*)d_in[3];
  const float* W1        = (const float*)d_in[4];
  const float* att_src1  = (const float*)d_in[5];
  const float* att_dst1  = (const float*)d_in[6];
  const float* We1       = (const float*)d_in[7];
  const float* att_edge1 = (const float*)d_in[8];
  const float* b1        = (const float*)d_in[9];
  const float* W2        = (const float*)d_in[10];
  const float* att_src2  = (const float*)d_in[11];
  const float* att_dst2  = (const float*)d_in[12];
  const float* We2       = (const float*)d_in[13];
  const float* att_edge2 = (const float*)d_in[14];
  const float* b2        = (const float*)d_in[15];
  const int* srcI = eidx;
  const int* dstI = eidx + NE;

  float* ws = (float*)d_ws;
  // layout (floats):
  __half* h1h   = (__half*)ws;               // NN*128 halfs = 3.2e6 floats (reused as h2h: NN*64 halfs)
  float* out1   = ws + 3200000;              // NN*128 f32 (reused as out2: NN*64)
  float* a_src1 = out1 + (long)NN * C1;      // NN*4
  float* a_dst1 = a_src1 + (long)NN * 4;     // NN*4
  float* ae1C   = a_dst1 + (long)NN * 4;     // NE*4
  float* ae2C   = ae1C + (long)NE * 4;       // NE
  int*   deg    = (int*)(ae2C + NE);         // NN
  int*   rowStart = deg + NN;                // NN+1 (pad to 50004)
  int*   cnt    = rowStart + 50004;          // NN
  int*   blockSums = cnt + NN;               // 256 (pad to 260)
  unsigned short* srcC = (unsigned short*)(blockSums + 260); // NE u16 = 4e5 floats
  float* sumEA  = (float*)srcC + 400000;     // 16
  float* meanEA = sumEA + 16;                // 16
  float* M1     = meanEA + 16;               // 64
  float* M2v    = M1 + 64;                   // 16
  float* aeSL1  = M2v + 16;                  // 4
  float* aeSL2  = aeSL1 + 4;                 // 4
  __half* h2h = h1h;                          // alias (h1h dead after agg1)
  float* out2 = out1;
  float* a_src2 = a_src1; float* a_dst2 = a_dst1;

  // ---- prep + CSR build ----
  hipMemsetAsync(sumEA, 0, 16 * sizeof(float), stream);
  hipMemsetAsync(deg, 0, NN * sizeof(int), stream);
  hipMemsetAsync(cnt, 0, NN * sizeof(int), stream);
  k_mean_ea<<<512, 256, 0, stream>>>(edge_attr, sumEA);
  k_prep<<<1, 128, 0, stream>>>(sumEA, We1, att_edge1, We2, att_edge2,
                                meanEA, M1, M2v, aeSL1, aeSL2);
  k_hist<<<cdiv(NE, 256), 256, 0, stream>>>(dstI, deg);
  k_scan1<<<NB, 256, 0, stream>>>(deg, rowStart, blockSums);
  k_scan2<<<1, 256, 0, stream>>>(blockSums);
  k_scan3<<<NB, 256, 0, stream>>>(rowStart, blockSums);
  k_scatter<<<cdiv(NE, 256), 256, 0, stream>>>(srcI, dstI, edge_attr, rowStart, cnt,
                                               M1, M2v, srcC, ae1C, ae2C);
  // ---- layer 1 ----
  k_gemm<<<dim3(cdiv(NN, 64), 2), 256, 0, stream>>>(x, W1, h1h, NN, C1, 128);
  k_attdot1<<<cdiv((long)NN * 4, 256), 256, 0, stream>>>(h1h, att_src1, att_dst1, a_src1, a_dst1);
  k_agg1<<<NN / 4, 256, 0, stream>>>(rowStart, srcC, ae1C, a_src1, a_dst1, aeSL1,
                                     h1h, b1, out1);
  // ---- layer 2 ----
  k_gemm<<<dim3(cdiv(NN, 64), 1), 256, 0, stream>>>(out1, W2, h2h, NN, OUTF, 128);
  k_attdot2<<<cdiv(NN, 256), 256, 0, stream>>>(h2h, att_src2, att_dst2, a_src2, a_dst2);
  k_agg2<<<NN / 4, 256, 0, stream>>>(rowStart, srcC, ae2C, a_src2, a_dst2, aeSL2,
                                     h2h, out2);
  // ---- pool ----
  k_pool<<<NG, 256, 0, stream>>>(out2, batch, b2, (float*)d_out);
}

// Round 5
// 423.955 us; speedup vs baseline: 6.6901x; 1.0945x over previous
//
#include <hip/hip_runtime.h>
#include <hip/hip_fp16.h>
#include <math.h>

#define NN 50000      // nodes
#define NE 800000     // edges (without self loops)
#define EDF 16        // edge feature dim
#define C1 128        // heads*hid layer1
#define HID 32
#define OUTF 64
#define NG 64
#define SLOPE 0.2f
#define NB 196        // scan blocks = cdiv(NN,256)
#define MAXE 256      // LDS-cached edges per node (fallback path beyond)
#define PB 256        // pool stage-1 blocks
#define PCH 196       // nodes per pool block = cdiv(NN,PB)

static inline int cdiv(long a, long b){ return (int)((a + b - 1) / b); }

__device__ __forceinline__ float lrelu(float x){ return x >= 0.f ? x : SLOPE * x; }

// ---- mean of edge_attr over rows ----
__global__ void k_mean_ea(const float* __restrict__ ea, float* __restrict__ sumEA){
  int c = threadIdx.x & 15;
  int r0 = threadIdx.x >> 4;
  float acc = 0.f;
  for (long r = (long)blockIdx.x * 16 + r0; r < NE; r += (long)gridDim.x * 16)
    acc += ea[r * EDF + c];
  __shared__ float s[256];
  s[threadIdx.x] = acc;
  __syncthreads();
  for (int stride = 128; stride >= 16; stride >>= 1){
    if (threadIdx.x < stride) s[threadIdx.x] += s[threadIdx.x + stride];
    __syncthreads();
  }
  if (threadIdx.x < 16) atomicAdd(&sumEA[c], s[threadIdx.x]);
}

// ---- tiny prep: meanEA, M1[4][16], M2[16], self-loop a_edge constants ----
__global__ void k_prep(const float* __restrict__ sumEA,
                       const float* __restrict__ We1, const float* __restrict__ att_e1,
                       const float* __restrict__ We2, const float* __restrict__ att_e2,
                       float* __restrict__ meanEA, float* __restrict__ M1,
                       float* __restrict__ M2, float* __restrict__ aeSL1,
                       float* __restrict__ aeSL2){
  int t = threadIdx.x; // 128 threads
  if (t < 16) meanEA[t] = sumEA[t] * (1.0f / NE);
  if (t < 64){
    int h = t >> 4, d = t & 15;
    float s = 0.f;
    for (int c = 0; c < HID; c++) s += We1[d * C1 + h * HID + c] * att_e1[h * HID + c];
    M1[h * 16 + d] = s;
  }
  if (t >= 64 && t < 80){
    int d = t - 64;
    float s = 0.f;
    for (int c = 0; c < OUTF; c++) s += We2[d * OUTF + c] * att_e2[c];
    M2[d] = s;
  }
  __syncthreads();
  if (t < 4){
    float s = 0.f;
    for (int d = 0; d < 16; d++) s += meanEA[d] * M1[t * 16 + d];
    aeSL1[t] = s;
  }
  if (t == 4){
    float s = 0.f;
    for (int d = 0; d < 16; d++) s += meanEA[d] * M2[d];
    *aeSL2 = s;
  }
}

// ---- CSR build: histogram of dst ----
__global__ void k_hist(const int* __restrict__ dst, int* __restrict__ deg){
  long e = (long)blockIdx.x * blockDim.x + threadIdx.x;
  if (e < NE) atomicAdd(&deg[dst[e]], 1);
}

// ---- scan step 1 ----
__global__ void k_scan1(const int* __restrict__ deg, int* __restrict__ rowStart,
                        int* __restrict__ blockSums){
  __shared__ int sd[256];
  int t = threadIdx.x;
  int i = blockIdx.x * 256 + t;
  int v = (i < NN) ? deg[i] : 0;
  sd[t] = v;
  __syncthreads();
  for (int off = 1; off < 256; off <<= 1){
    int add = (t >= off) ? sd[t - off] : 0;
    __syncthreads();
    sd[t] += add;
    __syncthreads();
  }
  int incl = sd[t];
  if (i < NN) rowStart[i] = incl - v;
  if (t == 255) blockSums[blockIdx.x] = incl;
}

// ---- scan step 2 ----
__global__ void k_scan2(int* __restrict__ blockSums){
  __shared__ int sd[256];
  int t = threadIdx.x;
  int v = (t < NB) ? blockSums[t] : 0;
  sd[t] = v;
  __syncthreads();
  for (int off = 1; off < 256; off <<= 1){
    int add = (t >= off) ? sd[t - off] : 0;
    __syncthreads();
    sd[t] += add;
    __syncthreads();
  }
  if (t < NB) blockSums[t] = sd[t] - v;
}

// ---- scan step 3 ----
__global__ void k_scan3(int* __restrict__ rowStart, const int* __restrict__ blockSums){
  int i = blockIdx.x * 256 + threadIdx.x;
  if (i < NN) rowStart[i] += blockSums[blockIdx.x];
  if (i == 0) rowStart[NN] = NE;
}

// ---- scatter: ONE packed 16B record per edge into dst-sorted order ----
// rec.x = src(u16) | ae2(f16)<<16 ; rec.y = half2(ae1[0],ae1[1]) ; rec.z = half2(ae1[2],ae1[3])
__global__ void k_scatter(const int* __restrict__ src, const int* __restrict__ dst,
                          const float* __restrict__ ea,
                          const int* __restrict__ rowStart, int* __restrict__ cnt,
                          const float* __restrict__ M1, const float* __restrict__ M2,
                          unsigned int* __restrict__ recC){
  __shared__ float sM1[64];
  __shared__ float sM2[16];
  int t = threadIdx.x;
  if (t < 64) sM1[t] = M1[t];
  if (t < 16) sM2[t] = M2[t];
  __syncthreads();
  long e = (long)blockIdx.x * blockDim.x + t;
  if (e >= NE) return;
  int d = dst[e];
  int s = src[e];
  int pos = rowStart[d] + atomicAdd(&cnt[d], 1);
  float eav[16];
  const float4* p = (const float4*)(ea + e * EDF);
  *(float4*)&eav[0]  = p[0]; *(float4*)&eav[4]  = p[1];
  *(float4*)&eav[8]  = p[2]; *(float4*)&eav[12] = p[3];
  float ae[4];
#pragma unroll
  for (int h = 0; h < 4; h++){
    float sdot = 0.f;
#pragma unroll
    for (int dd = 0; dd < 16; dd++) sdot += eav[dd] * sM1[h * 16 + dd];
    ae[h] = sdot;
  }
  float a2 = 0.f;
#pragma unroll
  for (int dd = 0; dd < 16; dd++) a2 += eav[dd] * sM2[dd];
  __half2 ae01 = __floats2half2_rn(ae[0], ae[1]);
  __half2 ae23 = __floats2half2_rn(ae[2], ae[3]);
  __half  a2h  = __float2half_rn(a2);
  uint4 rec;
  rec.x = (unsigned)s | ((unsigned)*(unsigned short*)&a2h << 16);
  rec.y = *(unsigned*)&ae01;
  rec.z = *(unsigned*)&ae23;
  rec.w = 0u;
  *(uint4*)&recC[(long)pos * 4] = rec;
}

// ---- f32 GEMM writing fp16: Ch[M,Ncols] = A[M,K] @ B[K,Ncols] ----
__global__ __launch_bounds__(256) void k_gemm(const float* __restrict__ A,
                                              const float* __restrict__ B,
                                              __half* __restrict__ Ch,
                                              int M, int Ncols, int K){
  __shared__ float As[16][64];
  __shared__ float Bs[16][64];
  int tid = threadIdx.x;
  int row0 = blockIdx.x * 64, col0 = blockIdx.y * 64;
  int tx = tid & 15, ty = tid >> 4;
  int lrow = tid >> 2, lkq = tid & 3;
  int bk = tid >> 4, bc = tid & 15;
  float acc[4][4] = {};
  for (int k0 = 0; k0 < K; k0 += 16){
    float4 a4 = make_float4(0.f, 0.f, 0.f, 0.f);
    int gr = row0 + lrow;
    if (gr < M) a4 = *(const float4*)&A[(long)gr * K + k0 + lkq * 4];
    As[lkq * 4 + 0][lrow] = a4.x; As[lkq * 4 + 1][lrow] = a4.y;
    As[lkq * 4 + 2][lrow] = a4.z; As[lkq * 4 + 3][lrow] = a4.w;
    *(float4*)&Bs[bk][bc * 4] = *(const float4*)&B[(long)(k0 + bk) * Ncols + col0 + bc * 4];
    __syncthreads();
#pragma unroll
    for (int k = 0; k < 16; k++){
      float4 a = *(float4*)&As[k][ty * 4];
      float4 b = *(float4*)&Bs[k][tx * 4];
      acc[0][0] += a.x*b.x; acc[0][1] += a.x*b.y; acc[0][2] += a.x*b.z; acc[0][3] += a.x*b.w;
      acc[1][0] += a.y*b.x; acc[1][1] += a.y*b.y; acc[1][2] += a.y*b.z; acc[1][3] += a.y*b.w;
      acc[2][0] += a.z*b.x; acc[2][1] += a.z*b.y; acc[2][2] += a.z*b.z; acc[2][3] += a.z*b.w;
      acc[3][0] += a.w*b.x; acc[3][1] += a.w*b.y; acc[3][2] += a.w*b.z; acc[3][3] += a.w*b.w;
    }
    __syncthreads();
  }
#pragma unroll
  for (int i = 0; i < 4; i++){
    int r = row0 + ty * 4 + i;
    if (r < M){
      __half2 p0 = __floats2half2_rn(acc[i][0], acc[i][1]);
      __half2 p1 = __floats2half2_rn(acc[i][2], acc[i][3]);
      uint2 pk;
      pk.x = *(unsigned int*)&p0;
      pk.y = *(unsigned int*)&p1;
      *(uint2*)&Ch[(long)r * Ncols + col0 + tx * 4] = pk;
    }
  }
}

// ---- layer1 attention dots (fp16 h) ----
__global__ void k_attdot1(const __half* __restrict__ h1h, const float* __restrict__ att_src,
                          const float* __restrict__ att_dst,
                          float* __restrict__ a_src, float* __restrict__ a_dst){
  long idx = (long)blockIdx.x * blockDim.x + threadIdx.x;
  if (idx >= (long)NN * 4) return;
  int h = (int)(idx & 3); long n = idx >> 2;
  const unsigned int* hp = (const unsigned int*)h1h + n * 64 + h * 16;
  float ss = 0.f, sd = 0.f;
#pragma unroll
  for (int i = 0; i < 16; i++){
    unsigned int u = hp[i];
    float2 f = __half22float2(*(__half2*)&u);
    ss += f.x * att_src[h * HID + 2*i] + f.y * att_src[h * HID + 2*i + 1];
    sd += f.x * att_dst[h * HID + 2*i] + f.y * att_dst[h * HID + 2*i + 1];
  }
  a_src[idx] = ss; a_dst[idx] = sd;
}

// ---- layer1 aggregation: 1 wave/node, lane-parallel softmax, fp16 gather ----
__global__ __launch_bounds__(256) void k_agg1(
    const int* __restrict__ rowStart, const unsigned int* __restrict__ recC,
    const float* __restrict__ a_src,
    const float* __restrict__ a_dst, const float* __restrict__ aeSL1,
    const __half* __restrict__ h1h, const float* __restrict__ b1,
    float* __restrict__ out1){
  __shared__ int   sS[4][MAXE];
  __shared__ float sC[4][MAXE * 4];
  int wid = threadIdx.x >> 6;
  int lane = threadIdx.x & 63;
  int n = blockIdx.x * 4 + wid;
  int start = rowStart[n];
  int dg = rowStart[n + 1] - start;
  float4 ad4 = *(const float4*)(a_dst + (long)n * 4);
  float4 as4 = *(const float4*)(a_src + (long)n * 4);
  float4 sl4 = *(const float4*)aeSL1;
  float4 aSelf;
  aSelf.x = lrelu(as4.x + ad4.x + sl4.x);
  aSelf.y = lrelu(as4.y + ad4.y + sl4.y);
  aSelf.z = lrelu(as4.z + ad4.z + sl4.z);
  aSelf.w = lrelu(as4.w + ad4.w + sl4.w);
  // phase A: lane-parallel alphas; chunk0 kept in registers, others in LDS
  float4 m = aSelf;
  float4 al0 = make_float4(0.f, 0.f, 0.f, 0.f);
  for (int j0 = 0; j0 < dg; j0 += 64){
    int j = j0 + lane;
    if (j < dg){
      uint4 rec = *(const uint4*)&recC[(long)(start + j) * 4];
      int s = rec.x & 0xffff;
      float2 ae01 = __half22float2(*(__half2*)&rec.y);
      float2 ae23 = __half22float2(*(__half2*)&rec.z);
      float4 asv = *(const float4*)(a_src + (long)s * 4);
      float4 al;
      al.x = lrelu(asv.x + ad4.x + ae01.x);
      al.y = lrelu(asv.y + ad4.y + ae01.y);
      al.z = lrelu(asv.z + ad4.z + ae23.x);
      al.w = lrelu(asv.w + ad4.w + ae23.y);
      m.x = fmaxf(m.x, al.x); m.y = fmaxf(m.y, al.y);
      m.z = fmaxf(m.z, al.z); m.w = fmaxf(m.w, al.w);
      if (j < MAXE) sS[wid][j] = s;
      if (j0 == 0) al0 = al;
      else if (j < MAXE) *(float4*)&sC[wid][j * 4] = al;
    }
  }
#pragma unroll
  for (int off = 32; off > 0; off >>= 1){
    m.x = fmaxf(m.x, __shfl_xor(m.x, off));
    m.y = fmaxf(m.y, __shfl_xor(m.y, off));
    m.z = fmaxf(m.z, __shfl_xor(m.z, off));
    m.w = fmaxf(m.w, __shfl_xor(m.w, off));
  }
  // phase B: c = exp(al - m), denominator partials, write c to LDS
  float4 dsum = make_float4(0.f, 0.f, 0.f, 0.f);
  for (int j0 = 0; j0 < dg; j0 += 64){
    int j = j0 + lane;
    if (j < dg){
      float4 al;
      if (j0 == 0) al = al0;
      else if (j < MAXE) al = *(float4*)&sC[wid][j * 4];
      else {
        uint4 rec = *(const uint4*)&recC[(long)(start + j) * 4];
        int s = rec.x & 0xffff;
        float2 ae01 = __half22float2(*(__half2*)&rec.y);
        float2 ae23 = __half22float2(*(__half2*)&rec.z);
        float4 asv = *(const float4*)(a_src + (long)s * 4);
        al.x = lrelu(asv.x + ad4.x + ae01.x);
        al.y = lrelu(asv.y + ad4.y + ae01.y);
        al.z = lrelu(asv.z + ad4.z + ae23.x);
        al.w = lrelu(asv.w + ad4.w + ae23.y);
      }
      float4 c;
      c.x = expf(al.x - m.x); c.y = expf(al.y - m.y);
      c.z = expf(al.z - m.z); c.w = expf(al.w - m.w);
      dsum.x += c.x; dsum.y += c.y; dsum.z += c.z; dsum.w += c.w;
      if (j < MAXE) *(float4*)&sC[wid][j * 4] = c;
    }
  }
#pragma unroll
  for (int off = 32; off > 0; off >>= 1){
    dsum.x += __shfl_xor(dsum.x, off);
    dsum.y += __shfl_xor(dsum.y, off);
    dsum.z += __shfl_xor(dsum.z, off);
    dsum.w += __shfl_xor(dsum.w, off);
  }
  float4 cSelf;
  cSelf.x = expf(aSelf.x - m.x); cSelf.y = expf(aSelf.y - m.y);
  cSelf.z = expf(aSelf.z - m.z); cSelf.w = expf(aSelf.w - m.w);
  // per-head scalars via real arrays (defined behavior; (&m.x)[h] is UB)
  float mA[4]  = {m.x, m.y, m.z, m.w};
  float adA[4] = {ad4.x, ad4.y, ad4.z, ad4.w};
  float csA[4] = {cSelf.x, cSelf.y, cSelf.z, cSelf.w};
  float invA[4];
  invA[0] = 1.f / (dsum.x + cSelf.x + 1e-16f);
  invA[1] = 1.f / (dsum.y + cSelf.y + 1e-16f);
  invA[2] = 1.f / (dsum.z + cSelf.z + 1e-16f);
  invA[3] = 1.f / (dsum.w + cSelf.w + 1e-16f);
  // pass 2: channel-parallel weighted gather (2 ch/lane), unrolled x4
  int ch = lane * 2;
  int h = lane >> 4;
  const unsigned int* hrow = (const unsigned int*)h1h;
  float cs   = csA[h];
  float vinv = invA[h];
  float mh   = mA[h];
  float adh  = adA[h];
  unsigned int hv = hrow[(long)n * 64 + lane];
  float2 hf = __half22float2(*(__half2*)&hv);
  float acc0 = hf.x * cs, acc1 = hf.y * cs;
  int jmax = dg < MAXE ? dg : MAXE;
  int j = 0;
  for (; j + 4 <= jmax; j += 4){
    int s0 = sS[wid][j+0], s1 = sS[wid][j+1], s2 = sS[wid][j+2], s3 = sS[wid][j+3];
    float c0 = sC[wid][(j+0)*4+h], c1 = sC[wid][(j+1)*4+h];
    float c2 = sC[wid][(j+2)*4+h], c3 = sC[wid][(j+3)*4+h];
    unsigned int v0 = hrow[(long)s0 * 64 + lane];
    unsigned int v1 = hrow[(long)s1 * 64 + lane];
    unsigned int v2 = hrow[(long)s2 * 64 + lane];
    unsigned int v3 = hrow[(long)s3 * 64 + lane];
    float2 f0 = __half22float2(*(__half2*)&v0);
    float2 f1 = __half22float2(*(__half2*)&v1);
    float2 f2 = __half22float2(*(__half2*)&v2);
    float2 f3 = __half22float2(*(__half2*)&v3);
    acc0 += c0 * f0.x + c1 * f1.x + c2 * f2.x + c3 * f3.x;
    acc1 += c0 * f0.y + c1 * f1.y + c2 * f2.y + c3 * f3.y;
  }
  for (; j < jmax; j++){
    int s = sS[wid][j];
    float c = sC[wid][j * 4 + h];
    unsigned int v = hrow[(long)s * 64 + lane];
    float2 f = __half22float2(*(__half2*)&v);
    acc0 += c * f.x; acc1 += c * f.y;
  }
  for (; j < dg; j++){ // rare fallback (dg > MAXE)
    uint4 rec = *(const uint4*)&recC[(long)(start + j) * 4];
    int s = rec.x & 0xffff;
    float2 ae01 = __half22float2(*(__half2*)&rec.y);
    float2 ae23 = __half22float2(*(__half2*)&rec.z);
    float aeA[4] = {ae01.x, ae01.y, ae23.x, ae23.y};
    float asv = a_src[(long)s * 4 + h];
    float c = expf(lrelu(asv + adh + aeA[h]) - mh);
    unsigned int v = hrow[(long)s * 64 + lane];
    float2 f = __half22float2(*(__half2*)&v);
    acc0 += c * f.x; acc1 += c * f.y;
  }
  float v0 = acc0 * vinv + b1[ch];
  float v1 = acc1 * vinv + b1[ch + 1];
  v0 = v0 > 0.f ? v0 : expf(v0) - 1.f;
  v1 = v1 > 0.f ? v1 : expf(v1) - 1.f;
  *(float2*)&out1[(long)n * C1 + ch] = make_float2(v0, v1);
}

// ---- layer2 attention dots (fp16 h, 1 head, 64 ch) ----
__global__ void k_attdot2(const __half* __restrict__ h2h, const float* __restrict__ att_src,
                          const float* __restrict__ att_dst,
                          float* __restrict__ a_src, float* __restrict__ a_dst){
  long n = (long)blockIdx.x * blockDim.x + threadIdx.x;
  if (n >= NN) return;
  const unsigned int* hp = (const unsigned int*)h2h + n * 32;
  float ss = 0.f, sd = 0.f;
#pragma unroll
  for (int i = 0; i < 32; i++){
    unsigned int u = hp[i];
    float2 f = __half22float2(*(__half2*)&u);
    ss += f.x * att_src[2*i] + f.y * att_src[2*i + 1];
    sd += f.x * att_dst[2*i] + f.y * att_dst[2*i + 1];
  }
  a_src[n] = ss; a_dst[n] = sd;
}

// ---- layer2 aggregation: 1 wave/node, fp16 gather ----
__global__ __launch_bounds__(256) void k_agg2(
    const int* __restrict__ rowStart, const unsigned int* __restrict__ recC,
    const float* __restrict__ a_src,
    const float* __restrict__ a_dst, const float* __restrict__ aeSL2,
    const __half* __restrict__ h2h, float* __restrict__ out2){
  __shared__ int   sS[4][MAXE];
  __shared__ float sC[4][MAXE];
  int wid = threadIdx.x >> 6;
  int lane = threadIdx.x & 63;
  int n = blockIdx.x * 4 + wid;
  int start = rowStart[n];
  int dg = rowStart[n + 1] - start;
  float adN = a_dst[n];
  float aSelf = lrelu(a_src[n] + adN + *aeSL2);
  float m = aSelf;
  float al0 = 0.f;
  for (int j0 = 0; j0 < dg; j0 += 64){
    int j = j0 + lane;
    if (j < dg){
      unsigned rx = recC[(long)(start + j) * 4];
      int s = rx & 0xffff;
      unsigned short ah = (unsigned short)(rx >> 16);
      float ae = __half2float(*(__half*)&ah);
      float al = lrelu(a_src[s] + adN + ae);
      m = fmaxf(m, al);
      if (j < MAXE) sS[wid][j] = s;
      if (j0 == 0) al0 = al;
      else if (j < MAXE) sC[wid][j] = al;
    }
  }
#pragma unroll
  for (int off = 32; off > 0; off >>= 1) m = fmaxf(m, __shfl_xor(m, off));
  float dsum = 0.f;
  for (int j0 = 0; j0 < dg; j0 += 64){
    int j = j0 + lane;
    if (j < dg){
      float al;
      if (j0 == 0) al = al0;
      else if (j < MAXE) al = sC[wid][j];
      else {
        unsigned rx = recC[(long)(start + j) * 4];
        int s = rx & 0xffff;
        unsigned short ah = (unsigned short)(rx >> 16);
        al = lrelu(a_src[s] + adN + __half2float(*(__half*)&ah));
      }
      float c = expf(al - m);
      dsum += c;
      if (j < MAXE) sC[wid][j] = c;
    }
  }
#pragma unroll
  for (int off = 32; off > 0; off >>= 1) dsum += __shfl_xor(dsum, off);
  float cSelf = expf(aSelf - m);
  float inv = 1.f / (dsum + cSelf + 1e-16f);
  float acc = __half2float(h2h[(long)n * OUTF + lane]) * cSelf;
  int jmax = dg < MAXE ? dg : MAXE;
  int j = 0;
  for (; j + 4 <= jmax; j += 4){
    int s0 = sS[wid][j+0], s1 = sS[wid][j+1], s2 = sS[wid][j+2], s3 = sS[wid][j+3];
    float c0 = sC[wid][j+0], c1 = sC[wid][j+1], c2 = sC[wid][j+2], c3 = sC[wid][j+3];
    float f0 = __half2float(h2h[(long)s0 * OUTF + lane]);
    float f1 = __half2float(h2h[(long)s1 * OUTF + lane]);
    float f2 = __half2float(h2h[(long)s2 * OUTF + lane]);
    float f3 = __half2float(h2h[(long)s3 * OUTF + lane]);
    acc += c0 * f0 + c1 * f1 + c2 * f2 + c3 * f3;
  }
  for (; j < jmax; j++)
    acc += sC[wid][j] * __half2float(h2h[(long)sS[wid][j] * OUTF + lane]);
  for (; j < dg; j++){ // rare fallback
    unsigned rx = recC[(long)(start + j) * 4];
    int s = rx & 0xffff;
    unsigned short ah = (unsigned short)(rx >> 16);
    float c = expf(lrelu(a_src[s] + adN + __half2float(*(__half*)&ah)) - m);
    acc += c * __half2float(h2h[(long)s * OUTF + lane]);
  }
  out2[(long)n * OUTF + lane] = acc * inv;
}

// ---- pool stage 1: segmented partial sums (batch sorted), flush atomics ----
__global__ __launch_bounds__(256) void k_pool1(const float* __restrict__ out2,
                                               const int* __restrict__ batch,
                                               float* __restrict__ gsum){
  int c = threadIdx.x & 63, r = threadIdx.x >> 6;
  int n0 = blockIdx.x * PCH + r;
  int n1 = blockIdx.x * PCH + PCH; if (n1 > NN) n1 = NN;
  float acc = 0.f; int curG = -1;
  for (int n = n0; n < n1; n += 4){
    int g = batch[n];
    if (g != curG){
      if (curG >= 0) atomicAdd(&gsum[curG * 64 + c], acc);
      curG = g; acc = 0.f;
    }
    acc += out2[(long)n * OUTF + c];
  }
  if (curG >= 0) atomicAdd(&gsum[curG * 64 + c], acc);
}

// ---- pool stage 2: bias + divide by count ----
__global__ void k_pool2(const float* __restrict__ gsum, const int* __restrict__ batch,
                        const float* __restrict__ b2, float* __restrict__ out){
  int g = blockIdx.x;
  int c = threadIdx.x; // 64
  int lo = 0, hi = NN;
  while (lo < hi){ int mid = (lo + hi) >> 1; if (batch[mid] < g) lo = mid + 1; else hi = mid; }
  int a = lo, b = NN;
  while (a < b){ int mid = (a + b) >> 1; if (batch[mid] < g + 1) a = mid + 1; else b = mid; }
  int cnt = a - lo;
  out[g * 64 + c] = (gsum[g * 64 + c] + (float)cnt * b2[c]) / fmaxf((float)cnt, 1.0f);
}

extern "C" void kernel_launch(void* const* d_in, const int* in_sizes, int n_in,
                              void* d_out, int out_size, void* d_ws, size_t ws_size,
                              hipStream_t stream) {
  const float* x         = (const float*)d_in[0];
  const int*   eidx      = (const int*)d_in[1];
  const float* edge_attr = (const float*)d_in[2];
  const int*   batch     = (const int*)d_in[3];
  const float* W1        = (const float*)d_in[4];
  const float* att_src1  = (const float*)d_in[5];
  const float* att_dst1  = (const float*)d_in[6];
  const float* We1       = (const float*)d_in[7];
  const float* att_edge1 = (const float*)d_in[8];
  const float* b1        = (const float*)d_in[9];
  const float* W2        = (const float*)d_in[10];
  const float* att_src2  = (const float*)d_in[11];
  const float* att_dst2  = (const float*)d_in[12];
  const float* We2       = (const float*)d_in[13];
  const float* att_edge2 = (const float*)d_in[14];
  const float* b2        = (const float*)d_in[15];
  const int* srcI = eidx;
  const int* dstI = eidx + NE;

  float* ws = (float*)d_ws;
  // layout (float units):
  __half* h1h   = (__half*)ws;               // NN*128 halfs = 3.2e6 floats (reused as h2h)
  float* out1   = ws + 3200000;              // NN*128 f32 (reused as out2: NN*64)
  float* a_src1 = out1 + (long)NN * C1;      // NN*4
  float* a_dst1 = a_src1 + (long)NN * 4;     // NN*4
  unsigned int* recC = (unsigned int*)(a_dst1 + (long)NN * 4); // NE*4 uints (16B/edge)
  int*   deg    = (int*)(recC + (long)NE * 4); // NN
  int*   rowStart = deg + NN;                // NN+1 (pad to 50004)
  int*   cnt    = rowStart + 50004;          // NN
  int*   blockSums = cnt + NN;               // 256 (pad to 260)
  float* gsum   = (float*)(blockSums + 260); // NG*64 = 4096
  float* sumEA  = gsum + NG * 64;            // 16
  float* meanEA = sumEA + 16;                // 16
  float* M1     = meanEA + 16;               // 64
  float* M2v    = M1 + 64;                   // 16
  float* aeSL1  = M2v + 16;                  // 4
  float* aeSL2  = aeSL1 + 4;                 // 4
  __half* h2h = h1h;                          // alias (h1h dead after agg1)
  float* out2 = out1;
  float* a_src2 = a_src1; float* a_dst2 = a_dst1;

  // ---- prep + CSR build ----
  hipMemsetAsync(sumEA, 0, 16 * sizeof(float), stream);
  hipMemsetAsync(deg, 0, NN * sizeof(int), stream);
  hipMemsetAsync(cnt, 0, NN * sizeof(int), stream);
  hipMemsetAsync(gsum, 0, NG * 64 * sizeof(float), stream);
  k_mean_ea<<<512, 256, 0, stream>>>(edge_attr, sumEA);
  k_prep<<<1, 128, 0, stream>>>(sumEA, We1, att_edge1, We2, att_edge2,
                                meanEA, M1, M2v, aeSL1, aeSL2);
  k_hist<<<cdiv(NE, 256), 256, 0, stream>>>(dstI, deg);
  k_scan1<<<NB, 256, 0, stream>>>(deg, rowStart, blockSums);
  k_scan2<<<1, 256, 0, stream>>>(blockSums);
  k_scan3<<<NB, 256, 0, stream>>>(rowStart, blockSums);
  k_scatter<<<cdiv(NE, 256), 256, 0, stream>>>(srcI, dstI, edge_attr, rowStart, cnt,
                                               M1, M2v, recC);
  // ---- layer 1 ----
  k_gemm<<<dim3(cdiv(NN, 64), 2), 256, 0, stream>>>(x, W1, h1h, NN, C1, 128);
  k_attdot1<<<cdiv((long)NN * 4, 256), 256, 0, stream>>>(h1h, att_src1, att_dst1, a_src1, a_dst1);
  k_agg1<<<NN / 4, 256, 0, stream>>>(rowStart, recC, a_src1, a_dst1, aeSL1,
                                     h1h, b1, out1);
  // ---- layer 2 ----
  k_gemm<<<dim3(cdiv(NN, 64), 1), 256, 0, stream>>>(out1, W2, h2h, NN, OUTF, 128);
  k_attdot2<<<cdiv(NN, 256), 256, 0, stream>>>(h2h, att_src2, att_dst2, a_src2, a_dst2);
  k_agg2<<<NN / 4, 256, 0, stream>>>(rowStart, recC, a_src2, a_dst2, aeSL2,
                                     h2h, out2);
  // ---- pool ----
  k_pool1<<<PB, 256, 0, stream>>>(out2, batch, gsum);
  k_pool2<<<NG, 64, 0, stream>>>(gsum, batch, b2, (float*)d_out);
}